// Round 2
// baseline (1084.789 us; speedup 1.0000x reference)
//
#include <hip/hip_runtime.h>
#include <hip/hip_bf16.h>

#define DEV __device__ __forceinline__

constexpr int N_ = 25000;
constexpr int P_ = 400000;

// ---------------- ws layout (units of 4 bytes) ----------------
constexpr int align4(int xx){ return (xx+3)&~3; }
constexpr int OFF_CNT     = 0;                          // N ints
constexpr int OFF_OFFSETS = align4(OFF_CNT + N_);       // N+1 ints
constexpr int OFF_CURSOR  = align4(OFF_OFFSETS + N_ + 1);
constexpr int OFF_SORTED  = align4(OFF_CURSOR + N_);    // P ints
constexpr int OFF_EDGE    = align4(OFF_SORTED + P_);    // P*16 dwords (32 bf16 edge feats, packed)
constexpr int OFF_E4      = OFF_EDGE + P_*16;           // P*4  f32 (exp(att) per head)
constexpr int OFF_DIR     = OFF_E4 + P_*4;              // P*4  f32 (x,y,z,d)
constexpr int WS_UNITS    = OFF_DIR + P_*4;             // ~10.1M dwords = 41 MB

// PhysNet RBF constants (K=50, r_max=0.5)
constexpr float MU0F  = 0.60653065971263342f;               // exp(-0.5)
constexpr float DMUF  = (1.0f - 0.60653065971263342f) / 49.0f;
constexpr float BETAF = 1.0f / ((0.04f * (1.0f - 0.60653065971263342f)) *
                                (0.04f * (1.0f - 0.60653065971263342f)));
constexpr float EPSF  = 1e-8f;

DEV float u2f(unsigned int u){ union{unsigned int i; float f;} c; c.i=u; return c.f; }
DEV unsigned int f2b16(float f){
  __hip_bfloat16 b = __float2bfloat16(f);
  unsigned short s; __builtin_memcpy(&s, &b, 2);
  return (unsigned int)s;
}
DEV unsigned int pack2(float a, float b){ return f2b16(a) | (f2b16(b) << 16); }
DEV float silu_f(float v){ return v / (1.0f + __expf(-v)); }

// ---------------- counting sort by idx_i ----------------
__global__ void k_hist(const int* __restrict__ idx_i, int* __restrict__ cnt){
  int t = blockIdx.x*256 + threadIdx.x;
  if (t < P_) atomicAdd(&cnt[idx_i[t]], 1);
}

__global__ __launch_bounds__(1024) void k_scan(const int* __restrict__ cnt,
                                               int* __restrict__ offsets,
                                               int* __restrict__ cursor){
  __shared__ int sd[1024];
  const int t = threadIdx.x;
  constexpr int CH = (N_ + 1023)/1024;   // 25
  int b = t*CH, e = b+CH;
  if (b > N_) b = N_;
  if (e > N_) e = N_;
  int s = 0;
  for (int q=b; q<e; q++) s += cnt[q];
  sd[t] = s; __syncthreads();
  for (int off=1; off<1024; off<<=1){
    int vv = (t >= off) ? sd[t-off] : 0;
    __syncthreads();
    sd[t] += vv;
    __syncthreads();
  }
  int run = sd[t] - s;                   // exclusive prefix
  for (int q=b; q<e; q++){ offsets[q] = run; cursor[q] = run; run += cnt[q]; }
  if (t == 1023) offsets[N_] = sd[1023];
}

__global__ void k_scatter(const int* __restrict__ idx_i, int* __restrict__ cursor,
                          int* __restrict__ sorted){
  int t = blockIdx.x*256 + threadIdx.x;
  if (t < P_){ int pos = atomicAdd(&cursor[idx_i[t]], 1); sorted[pos] = t; }
}

// ---------------- edge kernel: one thread per pair ----------------
// LDS SoA scratch: 89 packed-bf16 dwords per thread, layout [dword][tid].
// dwords 0..63  = h_cat (128 vals), dwords 64..88 = filtered (50 vals).
__global__ __launch_bounds__(128) void k_edge(
    const float* __restrict__ h, const float* __restrict__ x,
    const int* __restrict__ idx_i, const int* __restrict__ idx_j,
    const float* __restrict__ Wein, const float* __restrict__ bein,
    const float* __restrict__ Weo1, const float* __restrict__ beo1,
    const float* __restrict__ Weo2, const float* __restrict__ beo2,
    const float* __restrict__ Watt, const float* __restrict__ batt,
    unsigned int* __restrict__ edge_out, float* __restrict__ e4_out,
    float* __restrict__ dir_out)
{
  __shared__ unsigned int sq[89*128];
  const int tid = threadIdx.x;
  const int p = blockIdx.x*128 + tid;       // grid is exact: 3125*128 = 400000
  const int i = idx_i[p], j = idx_j[p];

  // geometry (fp32 inputs)
  float xi0 = x[i*3+0], xi1 = x[i*3+1], xi2 = x[i*3+2];
  float xj0 = x[j*3+0], xj1 = x[j*3+1], xj2 = x[j*3+2];
  float rx = xj0-xi0, ry = xj1-xi1, rz = xj2-xi2;
  float d  = sqrtf(rx*rx + ry*ry + rz*rz + EPSF);
  float iv = 1.0f/(d + EPSF);
  float dirx = rx*iv, diry = ry*iv, dirz = rz*iv;

  // stage h_i, h_j into LDS SoA as packed bf16: dword m = elements (2m, 2m+1)
  {
    const float4* hp = (const float4*)(h + (size_t)i*64);
    #pragma unroll
    for (int q=0;q<16;q++){ float4 u = hp[q];
      sq[(2*q+0)*128+tid] = pack2(u.x, u.y);
      sq[(2*q+1)*128+tid] = pack2(u.z, u.w); }
    const float4* jp = (const float4*)(h + (size_t)j*64);
    #pragma unroll
    for (int q=0;q<16;q++){ float4 u = jp[q];
      sq[(32+2*q+0)*128+tid] = pack2(u.x, u.y);
      sq[(32+2*q+1)*128+tid] = pack2(u.z, u.w); }
  }

  // phase A: filtered = rbf(d) * (hcat @ Wein + bein)
  float f[50];
  #pragma unroll
  for (int k=0;k<50;k++) f[k] = bein[k];
  for (int m2=0; m2<64; m2++){            // rolled; weight rows wave-uniform (s_load)
    unsigned int w = sq[m2*128+tid];
    float lo = u2f(w << 16);
    float hi = u2f(w & 0xffff0000u);
    const float* r0 = Wein + (2*m2)*50;
    const float* r1 = r0 + 50;
    #pragma unroll
    for (int k=0;k<50;k++) f[k] += lo*r0[k] + hi*r1[k];
  }
  {
    float emd = __expf(-d);
    #pragma unroll
    for (int k=0;k<50;k++){
      float t = emd - (MU0F + (float)k*DMUF);
      f[k] *= __expf(-BETAF*t*t);
    }
  }
  // write filtered (bf16-packed) into LDS dwords 64..88 (elements 128..177)
  #pragma unroll
  for (int k2=0;k2<25;k2++) sq[(64+k2)*128+tid] = pack2(f[2*k2], f[2*k2+1]);

  // phase B: layer 1 (179 -> 64); element 178 (= d/SCALE) applied separately
  float acc[64];
  #pragma unroll
  for (int o=0;o<64;o++) acc[o] = beo1[o];
  for (int m2=0; m2<89; m2++){
    unsigned int w = sq[m2*128+tid];
    float lo = u2f(w << 16);
    float hi = u2f(w & 0xffff0000u);
    const float* r0 = Weo1 + (2*m2)*64;
    const float* r1 = r0 + 64;
    #pragma unroll
    for (int o=0;o<64;o++) acc[o] += lo*r0[o] + hi*r1[o];
  }
  {
    const float* rd = Weo1 + 178*64;
    #pragma unroll
    for (int o=0;o<64;o++) acc[o] += d*rd[o];
  }
  // silu -> LDS (reuse dwords 0..63 as fp32)
  #pragma unroll
  for (int o=0;o<64;o++) sq[o*128+tid] = __float_as_uint(silu_f(acc[o]));
  // layer 2 (64 -> 32)
  float o2[32];
  #pragma unroll
  for (int c=0;c<32;c++) o2[c] = beo2[c];
  for (int o=0;o<64;o++){
    float s = __uint_as_float(sq[o*128+tid]);
    const float* r = Weo2 + o*32;
    #pragma unroll
    for (int c=0;c<32;c++) o2[c] += s*r[c];
  }
  // attention logits -> celu(alpha=2) -> exp (no max-shift: logits are small)
  float a0 = batt[0], a1 = batt[1], a2 = batt[2], a3 = batt[3];
  #pragma unroll
  for (int c=0;c<32;c++){
    const float* r = Watt + c*4;
    a0 += o2[c]*r[0]; a1 += o2[c]*r[1]; a2 += o2[c]*r[2]; a3 += o2[c]*r[3];
  }
  float e0 = __expf(a0 > 0.f ? a0 : 2.f*(__expf(a0*0.5f)-1.f));
  float e1 = __expf(a1 > 0.f ? a1 : 2.f*(__expf(a1*0.5f)-1.f));
  float e2 = __expf(a2 > 0.f ? a2 : 2.f*(__expf(a2*0.5f)-1.f));
  float e3 = __expf(a3 > 0.f ? a3 : 2.f*(__expf(a3*0.5f)-1.f));

  // stores: edge feats packed bf16 (dword m = o2[2m], o2[2m+1]); e4/dir fp32
  uint4* eo = (uint4*)(edge_out + (size_t)p*16);
  #pragma unroll
  for (int q=0;q<4;q++)
    eo[q] = make_uint4(pack2(o2[8*q+0],o2[8*q+1]), pack2(o2[8*q+2],o2[8*q+3]),
                       pack2(o2[8*q+4],o2[8*q+5]), pack2(o2[8*q+6],o2[8*q+7]));
  *(float4*)(e4_out + (size_t)p*4)  = make_float4(e0, e1, e2, e3);
  *(float4*)(dir_out + (size_t)p*4) = make_float4(dirx, diry, dirz, d);
}

// ---------------- node kernel: one wave (block=64) per node ----------------
__global__ void k_node(const float* __restrict__ h,
                       const float* __restrict__ x,
                       const float* __restrict__ v,
                       const int* __restrict__ offsets,
                       const int* __restrict__ sorted,
                       const unsigned int* __restrict__ edgeb,
                       const float* __restrict__ e4,
                       const float* __restrict__ dir4,
                       const float* __restrict__ Wxm, const float* __restrict__ Wvm,
                       const float* __restrict__ Wpn1, const float* __restrict__ bpn1,
                       const float* __restrict__ Wpn2, const float* __restrict__ bpn2,
                       const float* __restrict__ Wn1,  const float* __restrict__ bn1,
                       const float* __restrict__ Wn2,  const float* __restrict__ bn2,
                       const float* __restrict__ Wv1,  const float* __restrict__ bv1,
                       const float* __restrict__ Wv2,
                       float* __restrict__ out)
{
  __shared__ __align__(16) float sIn[256];
  __shared__ __align__(16) float sN2[32];
  __shared__ __align__(16) float sT[64];
  __shared__ __align__(16) float sT2[64];
  const int i = blockIdx.x;
  const int lane = threadIdx.x;
  const int n0 = offsets[i], n1 = offsets[i+1];
  const int cnt = n1 - n0;
  const int c = lane & 31;
  const int h0 = lane >> 5;
  const bool low = (lane < 32);

  // per-lane W_xm columns: wr0[e] = Wxm[(e*4+h0), c], wr1[e] = Wxm[(e*4+h0+2), c]
  float wr0[32], wr1[32];
  #pragma unroll
  for (int e=0;e<32;e++){ wr0[e] = Wxm[(e*4+h0)*32 + c]; wr1[e] = Wxm[(e*4+h0+2)*32 + c]; }
  const float wvm_c = Wvm[c];

  // pass A: softmax denominators per head
  float d0=0.f,d1=0.f,d2=0.f,d3=0.f;
  for (int s = n0 + lane; s < n1; s += 64){
    int p = sorted[s];
    const float4 ev = *(const float4*)(e4 + (size_t)p*4);
    d0+=ev.x; d1+=ev.y; d2+=ev.z; d3+=ev.w;
  }
  #pragma unroll
  for (int off=32; off>=1; off>>=1){
    d0 += __shfl_xor(d0,off); d1 += __shfl_xor(d1,off);
    d2 += __shfl_xor(d2,off); d3 += __shfl_xor(d3,off);
  }
  const float i0 = (cnt>0)?1.f/d0:0.f, i1 = (cnt>0)?1.f/d1:0.f;
  const float i2 = (cnt>0)?1.f/d2:0.f, i3 = (cnt>0)?1.f/d3:0.f;

  const int sb0 = lane & 1, sb1 = lane & 2;
  float semA=0.f, semB=0.f;
  float cx=0.f,cy=0.f,cz=0.f, gx=0.f,gy=0.f,gz=0.f;

  for (int s = n0; s < n1; ++s){
    const int p = __builtin_amdgcn_readfirstlane(sorted[s]);
    const float4 ev = *(const float4*)(e4 + (size_t)p*4);
    const float4 dv = *(const float4*)(dir4 + (size_t)p*4);
    const float aw0 = ev.x*i0, aw1 = ev.y*i1, aw2 = ev.z*i2, aw3 = ev.w*i3;
    const float awsel = sb1 ? (sb0 ? aw3 : aw2) : (sb0 ? aw1 : aw0);
    // edge value for this lane's channel c (packed bf16)
    unsigned int ew = edgeb[(size_t)p*16 + (c>>1)];
    float ec = (c & 1) ? u2f(ew & 0xffff0000u) : u2f(ew << 16);
    float eA = __shfl(ec, lane >> 2);            // edge[p, lane>>2]
    float eB = __shfl(ec, 16 + (lane >> 2));     // edge[p, 16 + (lane>>2)]
    semA += eA*awsel; semB += eB*awsel;          // h_i_sem[m=lane], [m=64+lane]
    // spatial: g = sum_e edge[p,e] * Wxm[e*4+h, c]
    float g0=0.f, g1=0.f;
    #pragma unroll
    for (int e=0;e<32;e+=8){
      uint4 u = *(const uint4*)(edgeb + (size_t)p*16 + (e>>1));
      float v0=u2f(u.x<<16), v1=u2f(u.x&0xffff0000u);
      float v2=u2f(u.y<<16), v3=u2f(u.y&0xffff0000u);
      float v4=u2f(u.z<<16), v5=u2f(u.z&0xffff0000u);
      float v6=u2f(u.w<<16), v7=u2f(u.w&0xffff0000u);
      g0 += v0*wr0[e]+v1*wr0[e+1]+v2*wr0[e+2]+v3*wr0[e+3]
          + v4*wr0[e+4]+v5*wr0[e+5]+v6*wr0[e+6]+v7*wr0[e+7];
      g1 += v0*wr1[e]+v1*wr1[e+1]+v2*wr1[e+2]+v3*wr1[e+3]
          + v4*wr1[e+4]+v5*wr1[e+5]+v6*wr1[e+6]+v7*wr1[e+7];
    }
    float awA = low ? aw0 : aw1;                 // head h0
    float awB = low ? aw2 : aw3;                 // head h0+2
    float tp = awA*g0 + awB*g1;
    tp += __shfl_xor(tp, 32);                    // full sum over 4 heads
    float tt = fminf(fmaxf(tp, -15.f), 15.f);
    float ex = __expf(2.f*tt);
    float th = (ex-1.f)/(ex+1.f);                // tanh
    if (low){
      cx += th*dv.x; cy += th*dv.y; cz += th*dv.z;
      float tw = th*wvm_c;
      gx += tw*dv.x; gy += tw*dv.y; gz += tw*dv.z;
    }
  }
  #pragma unroll
  for (int off=32; off>=1; off>>=1){
    gx += __shfl_xor(gx,off); gy += __shfl_xor(gy,off); gz += __shfl_xor(gz,off);
  }
  const float invc = 1.f/(float)(cnt > 1 ? cnt : 1);
  const float dvx = gx*invc, dvy = gy*invc, dvz = gz*invc;

  if (low){
    float mx = cx*invc, my = cy*invc, mz = cz*invc;
    sN2[c] = mx*mx + my*my + mz*mz;
  }
  sIn[lane]      = h[(size_t)i*64 + lane];
  sIn[64+lane]   = semA;
  sIn[128+lane]  = semB;
  __syncthreads();

  // spatial MLP: 32 -> 64 -> 64
  float s1 = bpn1[lane];
  #pragma unroll
  for (int cc=0;cc<32;cc++) s1 += sN2[cc]*Wpn1[cc*64+lane];
  s1 = silu_f(s1);
  sT[lane] = s1; __syncthreads();
  float s2 = bpn2[lane];
  for (int o=0;o<64;o+=4){
    const float4 t4 = *(const float4*)(&sT[o]);
    s2 += t4.x*Wpn2[o*64+lane] + t4.y*Wpn2[(o+1)*64+lane]
        + t4.z*Wpn2[(o+2)*64+lane] + t4.w*Wpn2[(o+3)*64+lane];
  }
  sIn[192+lane] = silu_f(s2);
  __syncthreads();

  // node MLP: 256 -> 64 -> 64, residual
  float b1 = bn1[lane];
  for (int m=0;m<256;m+=4){
    const float4 t4 = *(const float4*)(&sIn[m]);
    b1 += t4.x*Wn1[m*64+lane] + t4.y*Wn1[(m+1)*64+lane]
        + t4.z*Wn1[(m+2)*64+lane] + t4.w*Wn1[(m+3)*64+lane];
  }
  b1 = silu_f(b1);
  sT[lane] = b1; __syncthreads();
  float b2 = bn2[lane];
  for (int m=0;m<64;m+=4){
    const float4 t4 = *(const float4*)(&sT[m]);
    b2 += t4.x*Wn2[m*64+lane] + t4.y*Wn2[(m+1)*64+lane]
        + t4.z*Wn2[(m+2)*64+lane] + t4.w*Wn2[(m+3)*64+lane];
  }
  const float hnew = sIn[lane] + silu_f(b2);
  out[(size_t)i*64 + lane] = hnew;
  sT2[lane] = hnew; __syncthreads();

  // velocity gate: 64 -> 64 -> 1
  float c1 = bv1[lane];
  for (int m=0;m<64;m+=4){
    const float4 t4 = *(const float4*)(&sT2[m]);
    c1 += t4.x*Wv1[m*64+lane] + t4.y*Wv1[(m+1)*64+lane]
        + t4.z*Wv1[(m+2)*64+lane] + t4.w*Wv1[(m+3)*64+lane];
  }
  c1 = silu_f(c1);
  float gp = c1 * Wv2[lane];
  #pragma unroll
  for (int off=32; off>=1; off>>=1) gp += __shfl_xor(gp, off);
  const float gate = 2.f/(1.f + __expf(-gp));

  if (lane < 3){
    float vv = v[(size_t)i*3 + lane];
    float xx = x[(size_t)i*3 + lane];
    float ds = (lane==0) ? dvx : ((lane==1) ? dvy : dvz);
    float vn = gate*vv + ds;
    out[(size_t)N_*64 + (size_t)i*3 + lane]                 = xx + vn;
    out[(size_t)N_*64 + (size_t)N_*3 + (size_t)i*3 + lane]  = vn;
  }
}

// ---------------- launch ----------------
extern "C" void kernel_launch(void* const* d_in, const int* in_sizes, int n_in,
                              void* d_out, int out_size, void* d_ws, size_t ws_size,
                              hipStream_t stream)
{
  const float* h = (const float*)d_in[0];
  const float* x = (const float*)d_in[1];
  const float* v = (const float*)d_in[2];
  const int* idx_i = (const int*)d_in[3];
  const int* idx_j = (const int*)d_in[4];
  const float* Wein = (const float*)d_in[5];  const float* bein = (const float*)d_in[6];
  const float* Weo1 = (const float*)d_in[7];  const float* beo1 = (const float*)d_in[8];
  const float* Weo2 = (const float*)d_in[9];  const float* beo2 = (const float*)d_in[10];
  const float* Watt = (const float*)d_in[11]; const float* batt = (const float*)d_in[12];
  const float* Wxm  = (const float*)d_in[13]; const float* Wvm  = (const float*)d_in[14];
  const float* Wpn1 = (const float*)d_in[15]; const float* bpn1 = (const float*)d_in[16];
  const float* Wpn2 = (const float*)d_in[17]; const float* bpn2 = (const float*)d_in[18];
  const float* Wn1  = (const float*)d_in[19]; const float* bn1  = (const float*)d_in[20];
  const float* Wn2  = (const float*)d_in[21]; const float* bn2  = (const float*)d_in[22];
  const float* Wv1  = (const float*)d_in[23]; const float* bv1  = (const float*)d_in[24];
  const float* Wv2  = (const float*)d_in[25];

  float* wsf        = (float*)d_ws;
  int*   cnt        = (int*)(wsf + OFF_CNT);
  int*   offsets    = (int*)(wsf + OFF_OFFSETS);
  int*   cursor     = (int*)(wsf + OFF_CURSOR);
  int*   sorted     = (int*)(wsf + OFF_SORTED);
  unsigned int* edgeb = (unsigned int*)(wsf + OFF_EDGE);
  float* e4o        = wsf + OFF_E4;
  float* diro       = wsf + OFF_DIR;

  hipMemsetAsync(cnt, 0, N_*sizeof(int), stream);
  k_hist<<<(P_+255)/256, 256, 0, stream>>>(idx_i, cnt);
  k_scan<<<1, 1024, 0, stream>>>(cnt, offsets, cursor);
  k_scatter<<<(P_+255)/256, 256, 0, stream>>>(idx_i, cursor, sorted);
  k_edge<<<P_/128, 128, 0, stream>>>(h, x, idx_i, idx_j,
                                     Wein, bein, Weo1, beo1, Weo2, beo2, Watt, batt,
                                     edgeb, e4o, diro);
  k_node<<<N_, 64, 0, stream>>>(h, x, v, offsets, sorted, edgeb, e4o, diro,
                                Wxm, Wvm, Wpn1, bpn1, Wpn2, bpn2,
                                Wn1, bn1, Wn2, bn2, Wv1, bv1, Wv2,
                                (float*)d_out);
}

// Round 3
// 555.079 us; speedup vs baseline: 1.9543x; 1.9543x over previous
//
#include <hip/hip_runtime.h>
#include <hip/hip_bf16.h>

#define DEV __device__ __forceinline__

constexpr int N_ = 25000;
constexpr int P_ = 400000;

// ---------------- ws layout (units of 4 bytes) ----------------
constexpr int align4(int xx){ return (xx+3)&~3; }
constexpr int OFF_CNT     = 0;                          // N ints (dead after k_scan)
constexpr int OFF_OFFSETS = align4(OFF_CNT + N_);       // N+1 ints
constexpr int OFF_CURSOR  = align4(OFF_OFFSETS + N_ + 1);
constexpr int OFF_SORTED  = align4(OFF_CURSOR + N_);    // P ints
constexpr int OFF_EDGE    = align4(OFF_SORTED + P_);    // P*16 dwords (32 bf16 edge feats)
constexpr int OFF_E4      = OFF_EDGE + P_*16;           // P*4  f32 (exp(att) per head)
constexpr int OFF_DIR     = OFF_E4 + P_*4;              // P*4  f32 (x,y,z,d)
constexpr int WS_UNITS    = OFF_DIR + P_*4;             // ~10.1M dwords = 41 MB

// transposed bf16 weights overlaid on the dead cnt region (11264 dw <= 25000 dw)
constexpr int OFF_WB1 = OFF_CNT;          // [128 n][128 k] bf16 = 8192 dw
constexpr int OFF_WB2 = OFF_WB1 + 8192;   // [64 n][64 k]  bf16 = 2048 dw
constexpr int OFF_WB3 = OFF_WB2 + 2048;   // [32 n][64 k]  bf16 = 1024 dw

// PhysNet RBF constants (K=50, r_max=0.5)
constexpr float MU0F  = 0.60653065971263342f;               // exp(-0.5)
constexpr float DMUF  = (1.0f - 0.60653065971263342f) / 49.0f;
constexpr float BETAF = 1.0f / ((0.04f * (1.0f - 0.60653065971263342f)) *
                                (0.04f * (1.0f - 0.60653065971263342f)));
constexpr float EPSF  = 1e-8f;

DEV float u2f(unsigned int u){ union{unsigned int i; float f;} c; c.i=u; return c.f; }
DEV unsigned int f2b16(float f){
  __hip_bfloat16 b = __float2bfloat16(f);
  unsigned short s; __builtin_memcpy(&s, &b, 2);
  return (unsigned int)s;
}
DEV unsigned int pack2(float a, float b){ return f2b16(a) | (f2b16(b) << 16); }
DEV float silu_f(float v){ return v / (1.0f + __expf(-v)); }

using short8 = __attribute__((ext_vector_type(8))) short;   // 8 bf16 (4 VGPRs)
using f32x4  = __attribute__((ext_vector_type(4))) float;
union U4S8 { uint4 u; short8 s; };
DEV short8 ld_frag(const void* p){ U4S8 c; c.u = *(const uint4*)p; return c.s; }
DEV f32x4 mfma16(short8 a, short8 b, f32x4 c){
  return __builtin_amdgcn_mfma_f32_16x16x32_bf16(a, b, c, 0, 0, 0);
}

// ---------------- counting sort by idx_i ----------------
__global__ void k_hist(const int* __restrict__ idx_i, int* __restrict__ cnt){
  int t = blockIdx.x*256 + threadIdx.x;
  if (t < P_) atomicAdd(&cnt[idx_i[t]], 1);
}

__global__ __launch_bounds__(1024) void k_scan(const int* __restrict__ cnt,
                                               int* __restrict__ offsets,
                                               int* __restrict__ cursor){
  __shared__ int sd[1024];
  const int t = threadIdx.x;
  constexpr int CH = (N_ + 1023)/1024;   // 25
  int b = t*CH, e = b+CH;
  if (b > N_) b = N_;
  if (e > N_) e = N_;
  int s = 0;
  for (int q=b; q<e; q++) s += cnt[q];
  sd[t] = s; __syncthreads();
  for (int off=1; off<1024; off<<=1){
    int vv = (t >= off) ? sd[t-off] : 0;
    __syncthreads();
    sd[t] += vv;
    __syncthreads();
  }
  int run = sd[t] - s;                   // exclusive prefix
  for (int q=b; q<e; q++){ offsets[q] = run; cursor[q] = run; run += cnt[q]; }
  if (t == 1023) offsets[N_] = sd[1023];
}

__global__ void k_scatter(const int* __restrict__ idx_i, int* __restrict__ cursor,
                          int* __restrict__ sorted){
  int t = blockIdx.x*256 + threadIdx.x;
  if (t < P_){ int pos = atomicAdd(&cursor[idx_i[t]], 1); sorted[pos] = t; }
}

// ---------------- weight transpose/convert to bf16 [N][K] ----------------
// WB1: n<50 -> Wein[k][n]; 50<=n<64 -> 0; n>=64 -> Weo1[k][n-64]   (K=128 hcat)
// WB2: k<50 -> Weo1[128+k][n]; k==50 -> Weo1[178][n]; else 0       (K=64)
// WB3: Weo2[k][n]                                                  (K=64)
__global__ void k_prepw(const float* __restrict__ Wein, const float* __restrict__ Weo1,
                        const float* __restrict__ Weo2,
                        unsigned short* __restrict__ wb1, unsigned short* __restrict__ wb2,
                        unsigned short* __restrict__ wb3){
  int t = blockIdx.x*256 + threadIdx.x, st = gridDim.x*256;
  for (int q=t; q<128*128; q+=st){
    int n=q>>7, k=q&127;
    float v = (n<50) ? Wein[k*50+n] : ((n<64) ? 0.f : Weo1[k*64+(n-64)]);
    wb1[q] = (unsigned short)f2b16(v);
  }
  for (int q=t; q<64*64; q+=st){
    int n=q>>6, k=q&63;
    float v = (k<50) ? Weo1[(128+k)*64+n] : ((k==50) ? Weo1[178*64+n] : 0.f);
    wb2[q] = (unsigned short)f2b16(v);
  }
  for (int q=t; q<32*64; q+=st){
    int n=q>>6, k=q&63;
    wb3[q] = (unsigned short)f2b16(Weo2[k*32+n]);
  }
}

// ---------------- MFMA edge kernel ----------------
// Block = 256 threads = 4 fully independent waves; wave w owns pairs
// pbase+32w .. +31. LDS is wave-partitioned (row-aligned aliasing) -> no barriers.
// R1: A1 hcat [128 m][132 k] bf16 (264 B rows); later per-wave A3 [32][72] bf16
//     inside the wave's own A1 footprint (8448 B).
// R2: A2 [128 m][72 k] bf16 (144 B rows); later C3 f32 [128][36] (144 B rows, aliased).
__global__ __launch_bounds__(256, 3) void k_edge2(
    const float* __restrict__ h, const float* __restrict__ x,
    const int* __restrict__ idx_i, const int* __restrict__ idx_j,
    const unsigned short* __restrict__ wb1, const unsigned short* __restrict__ wb2,
    const unsigned short* __restrict__ wb3,
    const float* __restrict__ bein, const float* __restrict__ beo1,
    const float* __restrict__ beo2, const float* __restrict__ Watt,
    const float* __restrict__ batt,
    unsigned int* __restrict__ edge_out, float* __restrict__ e4_out,
    float* __restrict__ dir_out)
{
  __shared__ __align__(16) unsigned char sR1[128*264];   // 33792 B
  __shared__ __align__(16) unsigned char sR2[128*144];   // 18432 B
  __shared__ float sdv[128];
  __shared__ float semd[128];

  const int tid  = threadIdx.x;
  const int wv   = tid >> 6;
  const int lane = tid & 63;
  const int l15  = lane & 15;
  const int quad = lane >> 4;
  const int pbase = blockIdx.x * 128;

  // ---- geometry (lanes 0..31 of each wave; wave-local rows) ----
  if (lane < 32){
    int row = 32*wv + lane;
    int p2 = pbase + row;
    int ii = idx_i[p2], jj = idx_j[p2];
    float xi0=x[ii*3], xi1=x[ii*3+1], xi2=x[ii*3+2];
    float xj0=x[jj*3], xj1=x[jj*3+1], xj2=x[jj*3+2];
    float rx=xj0-xi0, ry=xj1-xi1, rz=xj2-xi2;
    float d = sqrtf(rx*rx+ry*ry+rz*rz+EPSF);
    float iv = 1.0f/(d+EPSF);
    sdv[row] = d;
    semd[row] = __expf(-d);
    *(float4*)(dir_out + (size_t)p2*4) = make_float4(rx*iv, ry*iv, rz*iv, d);
  }

  // ---- stage A1 = hcat bf16 (2 threads per row: halves i / j) ----
  {
    int rr = lane >> 1;
    int row = 32*wv + rr;
    int p1 = pbase + row;
    int hidx = (lane & 1) ? idx_j[p1] : idx_i[p1];
    const float4* hp = (const float4*)(h + (size_t)hidx*64);
    unsigned char* dst = sR1 + row*264 + (lane&1)*128;
    #pragma unroll
    for (int q=0;q<8;q++){
      float4 a = hp[2*q], b = hp[2*q+1];
      uint4 o = make_uint4(pack2(a.x,a.y), pack2(a.z,a.w), pack2(b.x,b.y), pack2(b.z,b.w));
      *(uint4*)(dst + q*16) = o;
    }
  }

  // ---- GEMM-1: [32 m x 128 k] @ [128 k x 128 n] ----
  // n 0..63: Wein (filtered pre-RBF, cols 50..63 zero);  n 64..127: Weo1-top partial
  f32x4 acc[2][8];
  #pragma unroll
  for (int mf=0; mf<2; mf++)
    #pragma unroll
    for (int nf=0; nf<8; nf++){
      float bias;
      if (nf < 4){ int nn = 16*nf + l15; bias = (nn < 50) ? bein[nn] : 0.f; }
      else       { bias = beo1[16*(nf-4) + l15]; }
      acc[mf][nf] = (f32x4){bias, bias, bias, bias};
    }
  #pragma unroll
  for (int s=0; s<4; s++){
    int koff = s*32 + quad*8;                       // bf16 k index
    short8 a0 = ld_frag(sR1 + (32*wv + l15)*264      + koff*2);
    short8 a1 = ld_frag(sR1 + (32*wv + 16 + l15)*264 + koff*2);
    #pragma unroll
    for (int nf=0; nf<8; nf++){
      short8 b = ld_frag((const unsigned char*)wb1 + (16*nf + l15)*256 + koff*2);
      acc[0][nf] = mfma16(a0, b, acc[0][nf]);
      acc[1][nf] = mfma16(a1, b, acc[1][nf]);
    }
  }

  // ---- epilogue 1: RBF filter -> A2 bf16 [row][k] (k=0..49 filtered, 50=d, 51..63=0) ----
  #pragma unroll
  for (int mf=0; mf<2; mf++)
    #pragma unroll
    for (int nf=0; nf<4; nf++){
      int n = 16*nf + l15;
      float mu = MU0F + (float)n*DMUF;
      #pragma unroll
      for (int reg=0; reg<4; reg++){
        int row = 32*wv + 16*mf + quad*4 + reg;
        float t = semd[row] - mu;
        float fv = acc[mf][nf][reg] * __expf(-BETAF*t*t);
        unsigned short ob;
        if (n < 50)       ob = (unsigned short)f2b16(fv);
        else if (n == 50) ob = (unsigned short)f2b16(sdv[row]);
        else              ob = 0;
        ((unsigned short*)sR2)[row*72 + n] = ob;
      }
    }

  // ---- GEMM-2: += A2 [32 x 64] @ WB2 [64 x 64]  (into layer-1 accs nf 4..7) ----
  #pragma unroll
  for (int s=0; s<2; s++){
    int koff = s*32 + quad*8;
    short8 a0 = ld_frag(sR2 + (32*wv + l15)*144      + koff*2);
    short8 a1 = ld_frag(sR2 + (32*wv + 16 + l15)*144 + koff*2);
    #pragma unroll
    for (int nf=0; nf<4; nf++){
      short8 b = ld_frag((const unsigned char*)wb2 + (16*nf + l15)*128 + koff*2);
      acc[0][4+nf] = mfma16(a0, b, acc[0][4+nf]);
      acc[1][4+nf] = mfma16(a1, b, acc[1][4+nf]);
    }
  }

  // ---- epilogue 2: silu -> A3 bf16 [rr][72] inside this wave's A1 footprint ----
  unsigned char* A3 = sR1 + 8448*wv;
  #pragma unroll
  for (int mf=0; mf<2; mf++)
    #pragma unroll
    for (int nf=0; nf<4; nf++){
      int n = 16*nf + l15;
      #pragma unroll
      for (int reg=0; reg<4; reg++){
        int rr = 16*mf + quad*4 + reg;
        ((unsigned short*)A3)[rr*72 + n] = (unsigned short)f2b16(silu_f(acc[mf][4+nf][reg]));
      }
    }

  // ---- GEMM-3: [32 x 64] @ WB3 [64 x 32] ----
  f32x4 acc3[2][2];
  #pragma unroll
  for (int mf=0; mf<2; mf++)
    #pragma unroll
    for (int nf=0; nf<2; nf++){
      float bias = beo2[16*nf + l15];
      acc3[mf][nf] = (f32x4){bias, bias, bias, bias};
    }
  #pragma unroll
  for (int s=0; s<2; s++){
    int koff = s*32 + quad*8;
    short8 a0 = ld_frag(A3 + (l15)*144      + koff*2);
    short8 a1 = ld_frag(A3 + (16 + l15)*144 + koff*2);
    #pragma unroll
    for (int nf=0; nf<2; nf++){
      short8 b = ld_frag((const unsigned char*)wb3 + (16*nf + l15)*128 + koff*2);
      acc3[0][nf] = mfma16(a0, b, acc3[0][nf]);
      acc3[1][nf] = mfma16(a1, b, acc3[1][nf]);
    }
  }

  // ---- epilogue 3: C3 f32 -> sR2 rows (row-aligned alias of dead A2) ----
  #pragma unroll
  for (int mf=0; mf<2; mf++)
    #pragma unroll
    for (int nf=0; nf<2; nf++){
      int n = 16*nf + l15;
      #pragma unroll
      for (int reg=0; reg<4; reg++){
        int row = 32*wv + 16*mf + quad*4 + reg;
        ((float*)sR2)[row*36 + n] = acc3[mf][nf][reg];
      }
    }

  // ---- attention + stores (2 lanes per row, wave-local) ----
  {
    int rr = lane >> 1;
    int row = 32*wv + rr;
    int p = pbase + row;
    int cb = (lane & 1) * 16;
    const float* er = (const float*)sR2 + row*36;
    float l0, l1, l2, l3;
    if ((lane & 1) == 0){ l0 = batt[0]; l1 = batt[1]; l2 = batt[2]; l3 = batt[3]; }
    else                { l0 = l1 = l2 = l3 = 0.f; }
    float ecache[16];
    #pragma unroll
    for (int c=0;c<16;c++){
      float ev = er[cb + c];
      ecache[c] = ev;
      const float4 wr = *(const float4*)(Watt + (cb + c)*4);
      l0 += ev*wr.x; l1 += ev*wr.y; l2 += ev*wr.z; l3 += ev*wr.w;
    }
    l0 += __shfl_xor(l0,1); l1 += __shfl_xor(l1,1);
    l2 += __shfl_xor(l2,1); l3 += __shfl_xor(l3,1);
    if ((lane & 1) == 0){
      float e0 = __expf(l0 > 0.f ? l0 : 2.f*(__expf(l0*0.5f)-1.f));
      float e1 = __expf(l1 > 0.f ? l1 : 2.f*(__expf(l1*0.5f)-1.f));
      float e2 = __expf(l2 > 0.f ? l2 : 2.f*(__expf(l2*0.5f)-1.f));
      float e3 = __expf(l3 > 0.f ? l3 : 2.f*(__expf(l3*0.5f)-1.f));
      *(float4*)(e4_out + (size_t)p*4) = make_float4(e0, e1, e2, e3);
    }
    // store this half-row of edge feats as packed bf16 (8 dwords)
    uint4 o1 = make_uint4(pack2(ecache[0],ecache[1]),  pack2(ecache[2],ecache[3]),
                          pack2(ecache[4],ecache[5]),  pack2(ecache[6],ecache[7]));
    uint4 o2 = make_uint4(pack2(ecache[8],ecache[9]),  pack2(ecache[10],ecache[11]),
                          pack2(ecache[12],ecache[13]),pack2(ecache[14],ecache[15]));
    unsigned int* ep = edge_out + (size_t)p*16 + (lane&1)*8;
    *(uint4*)(ep)     = o1;
    *(uint4*)(ep + 4) = o2;
  }
}

// ---------------- node kernel: one wave (block=64) per node (unchanged) ----------------
__global__ void k_node(const float* __restrict__ h,
                       const float* __restrict__ x,
                       const float* __restrict__ v,
                       const int* __restrict__ offsets,
                       const int* __restrict__ sorted,
                       const unsigned int* __restrict__ edgeb,
                       const float* __restrict__ e4,
                       const float* __restrict__ dir4,
                       const float* __restrict__ Wxm, const float* __restrict__ Wvm,
                       const float* __restrict__ Wpn1, const float* __restrict__ bpn1,
                       const float* __restrict__ Wpn2, const float* __restrict__ bpn2,
                       const float* __restrict__ Wn1,  const float* __restrict__ bn1,
                       const float* __restrict__ Wn2,  const float* __restrict__ bn2,
                       const float* __restrict__ Wv1,  const float* __restrict__ bv1,
                       const float* __restrict__ Wv2,
                       float* __restrict__ out)
{
  __shared__ __align__(16) float sIn[256];
  __shared__ __align__(16) float sN2[32];
  __shared__ __align__(16) float sT[64];
  __shared__ __align__(16) float sT2[64];
  const int i = blockIdx.x;
  const int lane = threadIdx.x;
  const int n0 = offsets[i], n1 = offsets[i+1];
  const int cnt = n1 - n0;
  const int c = lane & 31;
  const int h0 = lane >> 5;
  const bool low = (lane < 32);

  float wr0[32], wr1[32];
  #pragma unroll
  for (int e=0;e<32;e++){ wr0[e] = Wxm[(e*4+h0)*32 + c]; wr1[e] = Wxm[(e*4+h0+2)*32 + c]; }
  const float wvm_c = Wvm[c];

  float d0=0.f,d1=0.f,d2=0.f,d3=0.f;
  for (int s = n0 + lane; s < n1; s += 64){
    int p = sorted[s];
    const float4 ev = *(const float4*)(e4 + (size_t)p*4);
    d0+=ev.x; d1+=ev.y; d2+=ev.z; d3+=ev.w;
  }
  #pragma unroll
  for (int off=32; off>=1; off>>=1){
    d0 += __shfl_xor(d0,off); d1 += __shfl_xor(d1,off);
    d2 += __shfl_xor(d2,off); d3 += __shfl_xor(d3,off);
  }
  const float i0 = (cnt>0)?1.f/d0:0.f, i1 = (cnt>0)?1.f/d1:0.f;
  const float i2 = (cnt>0)?1.f/d2:0.f, i3 = (cnt>0)?1.f/d3:0.f;

  const int sb0 = lane & 1, sb1 = lane & 2;
  float semA=0.f, semB=0.f;
  float cx=0.f,cy=0.f,cz=0.f, gx=0.f,gy=0.f,gz=0.f;

  for (int s = n0; s < n1; ++s){
    const int p = __builtin_amdgcn_readfirstlane(sorted[s]);
    const float4 ev = *(const float4*)(e4 + (size_t)p*4);
    const float4 dv = *(const float4*)(dir4 + (size_t)p*4);
    const float aw0 = ev.x*i0, aw1 = ev.y*i1, aw2 = ev.z*i2, aw3 = ev.w*i3;
    const float awsel = sb1 ? (sb0 ? aw3 : aw2) : (sb0 ? aw1 : aw0);
    unsigned int ew = edgeb[(size_t)p*16 + (c>>1)];
    float ec = (c & 1) ? u2f(ew & 0xffff0000u) : u2f(ew << 16);
    float eA = __shfl(ec, lane >> 2);
    float eB = __shfl(ec, 16 + (lane >> 2));
    semA += eA*awsel; semB += eB*awsel;
    float g0=0.f, g1=0.f;
    #pragma unroll
    for (int e=0;e<32;e+=8){
      uint4 u = *(const uint4*)(edgeb + (size_t)p*16 + (e>>1));
      float v0=u2f(u.x<<16), v1=u2f(u.x&0xffff0000u);
      float v2=u2f(u.y<<16), v3=u2f(u.y&0xffff0000u);
      float v4=u2f(u.z<<16), v5=u2f(u.z&0xffff0000u);
      float v6=u2f(u.w<<16), v7=u2f(u.w&0xffff0000u);
      g0 += v0*wr0[e]+v1*wr0[e+1]+v2*wr0[e+2]+v3*wr0[e+3]
          + v4*wr0[e+4]+v5*wr0[e+5]+v6*wr0[e+6]+v7*wr0[e+7];
      g1 += v0*wr1[e]+v1*wr1[e+1]+v2*wr1[e+2]+v3*wr1[e+3]
          + v4*wr1[e+4]+v5*wr1[e+5]+v6*wr1[e+6]+v7*wr1[e+7];
    }
    float awA = low ? aw0 : aw1;
    float awB = low ? aw2 : aw3;
    float tp = awA*g0 + awB*g1;
    tp += __shfl_xor(tp, 32);
    float tt = fminf(fmaxf(tp, -15.f), 15.f);
    float ex = __expf(2.f*tt);
    float th = (ex-1.f)/(ex+1.f);
    if (low){
      cx += th*dv.x; cy += th*dv.y; cz += th*dv.z;
      float tw = th*wvm_c;
      gx += tw*dv.x; gy += tw*dv.y; gz += tw*dv.z;
    }
  }
  #pragma unroll
  for (int off=32; off>=1; off>>=1){
    gx += __shfl_xor(gx,off); gy += __shfl_xor(gy,off); gz += __shfl_xor(gz,off);
  }
  const float invc = 1.f/(float)(cnt > 1 ? cnt : 1);
  const float dvx = gx*invc, dvy = gy*invc, dvz = gz*invc;

  if (low){
    float mx = cx*invc, my = cy*invc, mz = cz*invc;
    sN2[c] = mx*mx + my*my + mz*mz;
  }
  sIn[lane]      = h[(size_t)i*64 + lane];
  sIn[64+lane]   = semA;
  sIn[128+lane]  = semB;
  __syncthreads();

  float s1 = bpn1[lane];
  #pragma unroll
  for (int cc=0;cc<32;cc++) s1 += sN2[cc]*Wpn1[cc*64+lane];
  s1 = silu_f(s1);
  sT[lane] = s1; __syncthreads();
  float s2 = bpn2[lane];
  for (int o=0;o<64;o+=4){
    const float4 t4 = *(const float4*)(&sT[o]);
    s2 += t4.x*Wpn2[o*64+lane] + t4.y*Wpn2[(o+1)*64+lane]
        + t4.z*Wpn2[(o+2)*64+lane] + t4.w*Wpn2[(o+3)*64+lane];
  }
  sIn[192+lane] = silu_f(s2);
  __syncthreads();

  float b1 = bn1[lane];
  for (int m=0;m<256;m+=4){
    const float4 t4 = *(const float4*)(&sIn[m]);
    b1 += t4.x*Wn1[m*64+lane] + t4.y*Wn1[(m+1)*64+lane]
        + t4.z*Wn1[(m+2)*64+lane] + t4.w*Wn1[(m+3)*64+lane];
  }
  b1 = silu_f(b1);
  sT[lane] = b1; __syncthreads();
  float b2 = bn2[lane];
  for (int m=0;m<64;m+=4){
    const float4 t4 = *(const float4*)(&sT[m]);
    b2 += t4.x*Wn2[m*64+lane] + t4.y*Wn2[(m+1)*64+lane]
        + t4.z*Wn2[(m+2)*64+lane] + t4.w*Wn2[(m+3)*64+lane];
  }
  const float hnew = sIn[lane] + silu_f(b2);
  out[(size_t)i*64 + lane] = hnew;
  sT2[lane] = hnew; __syncthreads();

  float c1 = bv1[lane];
  for (int m=0;m<64;m+=4){
    const float4 t4 = *(const float4*)(&sT2[m]);
    c1 += t4.x*Wv1[m*64+lane] + t4.y*Wv1[(m+1)*64+lane]
        + t4.z*Wv1[(m+2)*64+lane] + t4.w*Wv1[(m+3)*64+lane];
  }
  c1 = silu_f(c1);
  float gp = c1 * Wv2[lane];
  #pragma unroll
  for (int off=32; off>=1; off>>=1) gp += __shfl_xor(gp, off);
  const float gate = 2.f/(1.f + __expf(-gp));

  if (lane < 3){
    float vv = v[(size_t)i*3 + lane];
    float xx = x[(size_t)i*3 + lane];
    float ds = (lane==0) ? dvx : ((lane==1) ? dvy : dvz);
    float vn = gate*vv + ds;
    out[(size_t)N_*64 + (size_t)i*3 + lane]                 = xx + vn;
    out[(size_t)N_*64 + (size_t)N_*3 + (size_t)i*3 + lane]  = vn;
  }
}

// ---------------- launch ----------------
extern "C" void kernel_launch(void* const* d_in, const int* in_sizes, int n_in,
                              void* d_out, int out_size, void* d_ws, size_t ws_size,
                              hipStream_t stream)
{
  const float* h = (const float*)d_in[0];
  const float* x = (const float*)d_in[1];
  const float* v = (const float*)d_in[2];
  const int* idx_i = (const int*)d_in[3];
  const int* idx_j = (const int*)d_in[4];
  const float* Wein = (const float*)d_in[5];  const float* bein = (const float*)d_in[6];
  const float* Weo1 = (const float*)d_in[7];  const float* beo1 = (const float*)d_in[8];
  const float* Weo2 = (const float*)d_in[9];  const float* beo2 = (const float*)d_in[10];
  const float* Watt = (const float*)d_in[11]; const float* batt = (const float*)d_in[12];
  const float* Wxm  = (const float*)d_in[13]; const float* Wvm  = (const float*)d_in[14];
  const float* Wpn1 = (const float*)d_in[15]; const float* bpn1 = (const float*)d_in[16];
  const float* Wpn2 = (const float*)d_in[17]; const float* bpn2 = (const float*)d_in[18];
  const float* Wn1  = (const float*)d_in[19]; const float* bn1  = (const float*)d_in[20];
  const float* Wn2  = (const float*)d_in[21]; const float* bn2  = (const float*)d_in[22];
  const float* Wv1  = (const float*)d_in[23]; const float* bv1  = (const float*)d_in[24];
  const float* Wv2  = (const float*)d_in[25];

  float* wsf        = (float*)d_ws;
  int*   cnt        = (int*)(wsf + OFF_CNT);
  int*   offsets    = (int*)(wsf + OFF_OFFSETS);
  int*   cursor     = (int*)(wsf + OFF_CURSOR);
  int*   sorted     = (int*)(wsf + OFF_SORTED);
  unsigned int* edgeb = (unsigned int*)(wsf + OFF_EDGE);
  float* e4o        = wsf + OFF_E4;
  float* diro       = wsf + OFF_DIR;
  unsigned short* wb1 = (unsigned short*)(wsf + OFF_WB1);
  unsigned short* wb2 = (unsigned short*)(wsf + OFF_WB2);
  unsigned short* wb3 = (unsigned short*)(wsf + OFF_WB3);

  hipMemsetAsync(cnt, 0, N_*sizeof(int), stream);
  k_hist<<<(P_+255)/256, 256, 0, stream>>>(idx_i, cnt);
  k_scan<<<1, 1024, 0, stream>>>(cnt, offsets, cursor);
  // cnt dead after scan -> overlay transposed weights there
  k_prepw<<<32, 256, 0, stream>>>(Wein, Weo1, Weo2, wb1, wb2, wb3);
  k_scatter<<<(P_+255)/256, 256, 0, stream>>>(idx_i, cursor, sorted);
  k_edge2<<<P_/128, 256, 0, stream>>>(h, x, idx_i, idx_j, wb1, wb2, wb3,
                                      bein, beo1, beo2, Watt, batt,
                                      edgeb, e4o, diro);
  k_node<<<N_, 64, 0, stream>>>(h, x, v, offsets, sorted, edgeb, e4o, diro,
                                Wxm, Wvm, Wpn1, bpn1, Wpn2, bpn2,
                                Wn1, bn1, Wn2, bn2, Wv1, bv1, Wv2,
                                (float*)d_out);
}

// Round 4
// 458.607 us; speedup vs baseline: 2.3654x; 1.2104x over previous
//
#include <hip/hip_runtime.h>
#include <hip/hip_bf16.h>

#define DEV __device__ __forceinline__

constexpr int N_ = 25000;
constexpr int P_ = 400000;

// ---------------- ws layout (units of 4 bytes) ----------------
constexpr int align4(int xx){ return (xx+3)&~3; }
constexpr int OFF_CNT     = 0;                          // N ints (dead after k_scan)
constexpr int OFF_OFFSETS = align4(OFF_CNT + N_);       // N+1 ints
constexpr int OFF_CURSOR  = align4(OFF_OFFSETS + N_ + 1);
constexpr int OFF_SORTED  = align4(OFF_CURSOR + N_);    // P ints
constexpr int OFF_EDGE    = align4(OFF_SORTED + P_);    // P*16 dwords (32 bf16 edge feats)
constexpr int OFF_E4      = OFF_EDGE + P_*16;           // P*4  f32 (exp(att) per head)
constexpr int OFF_DIR     = OFF_E4 + P_*4;              // P*4  f32 (x,y,z,d)
constexpr int WS_UNITS    = OFF_DIR + P_*4;             // ~10.1M dwords = 41 MB

// transposed bf16 weights overlaid on the dead cnt region (13312 dw <= 25000 dw)
constexpr int OFF_WB1 = OFF_CNT;          // [128 n][128 k] bf16 = 8192 dw
constexpr int OFF_WB2 = OFF_WB1 + 8192;   // [64 n][64 k]  bf16 = 2048 dw
constexpr int OFF_WB3 = OFF_WB2 + 2048;   // [32 n][64 k]  bf16 = 1024 dw
constexpr int OFF_WB4 = OFF_WB3 + 1024;   // [128 n][32 k] bf16 = 2048 dw (Wxm^T, n=4c+h)

// PhysNet RBF constants (K=50, r_max=0.5)
constexpr float MU0F  = 0.60653065971263342f;               // exp(-0.5)
constexpr float DMUF  = (1.0f - 0.60653065971263342f) / 49.0f;
constexpr float BETAF = 1.0f / ((0.04f * (1.0f - 0.60653065971263342f)) *
                                (0.04f * (1.0f - 0.60653065971263342f)));
constexpr float EPSF  = 1e-8f;

DEV float u2f(unsigned int u){ union{unsigned int i; float f;} c; c.i=u; return c.f; }
DEV unsigned int f2b16(float f){
  __hip_bfloat16 b = __float2bfloat16(f);
  unsigned short s; __builtin_memcpy(&s, &b, 2);
  return (unsigned int)s;
}
DEV unsigned int pack2(float a, float b){ return f2b16(a) | (f2b16(b) << 16); }
DEV float silu_f(float v){ return v / (1.0f + __expf(-v)); }

using short8 = __attribute__((ext_vector_type(8))) short;   // 8 bf16 (4 VGPRs)
using f32x4  = __attribute__((ext_vector_type(4))) float;
union U4S8 { uint4 u; short8 s; };
DEV short8 ld_frag(const void* p){ U4S8 c; c.u = *(const uint4*)p; return c.s; }
DEV f32x4 mfma16(short8 a, short8 b, f32x4 c){
  return __builtin_amdgcn_mfma_f32_16x16x32_bf16(a, b, c, 0, 0, 0);
}

// ---------------- counting sort by idx_i ----------------
__global__ void k_hist(const int* __restrict__ idx_i, int* __restrict__ cnt){
  int t = blockIdx.x*256 + threadIdx.x;
  if (t < P_) atomicAdd(&cnt[idx_i[t]], 1);
}

__global__ __launch_bounds__(1024) void k_scan(const int* __restrict__ cnt,
                                               int* __restrict__ offsets,
                                               int* __restrict__ cursor){
  __shared__ int sd[1024];
  const int t = threadIdx.x;
  constexpr int CH = (N_ + 1023)/1024;   // 25
  int b = t*CH, e = b+CH;
  if (b > N_) b = N_;
  if (e > N_) e = N_;
  int s = 0;
  for (int q=b; q<e; q++) s += cnt[q];
  sd[t] = s; __syncthreads();
  for (int off=1; off<1024; off<<=1){
    int vv = (t >= off) ? sd[t-off] : 0;
    __syncthreads();
    sd[t] += vv;
    __syncthreads();
  }
  int run = sd[t] - s;                   // exclusive prefix
  for (int q=b; q<e; q++){ offsets[q] = run; cursor[q] = run; run += cnt[q]; }
  if (t == 1023) offsets[N_] = sd[1023];
}

__global__ void k_scatter(const int* __restrict__ idx_i, int* __restrict__ cursor,
                          int* __restrict__ sorted){
  int t = blockIdx.x*256 + threadIdx.x;
  if (t < P_){ int pos = atomicAdd(&cursor[idx_i[t]], 1); sorted[pos] = t; }
}

// ---------------- weight transpose/convert to bf16 [N][K] ----------------
__global__ void k_prepw(const float* __restrict__ Wein, const float* __restrict__ Weo1,
                        const float* __restrict__ Weo2, const float* __restrict__ Wxm,
                        unsigned short* __restrict__ wb1, unsigned short* __restrict__ wb2,
                        unsigned short* __restrict__ wb3, unsigned short* __restrict__ wb4){
  int t = blockIdx.x*256 + threadIdx.x, st = gridDim.x*256;
  for (int q=t; q<128*128; q+=st){
    int n=q>>7, k=q&127;
    float v = (n<50) ? Wein[k*50+n] : ((n<64) ? 0.f : Weo1[k*64+(n-64)]);
    wb1[q] = (unsigned short)f2b16(v);
  }
  for (int q=t; q<64*64; q+=st){
    int n=q>>6, k=q&63;
    float v = (k<50) ? Weo1[(128+k)*64+n] : ((k==50) ? Weo1[178*64+n] : 0.f);
    wb2[q] = (unsigned short)f2b16(v);
  }
  for (int q=t; q<32*64; q+=st){
    int n=q>>6, k=q&63;
    wb3[q] = (unsigned short)f2b16(Weo2[k*32+n]);
  }
  // wb4[n][k] with n = 4c+h, k = e:  Wxm[e*4+h, c]
  for (int q=t; q<128*32; q+=st){
    int n=q>>5, k=q&31;
    int cc = n>>2, hh = n&3;
    wb4[q] = (unsigned short)f2b16(Wxm[(k*4+hh)*32 + cc]);
  }
}

// ---------------- MFMA edge kernel (unchanged from round 3) ----------------
__global__ __launch_bounds__(256, 3) void k_edge2(
    const float* __restrict__ h, const float* __restrict__ x,
    const int* __restrict__ idx_i, const int* __restrict__ idx_j,
    const unsigned short* __restrict__ wb1, const unsigned short* __restrict__ wb2,
    const unsigned short* __restrict__ wb3,
    const float* __restrict__ bein, const float* __restrict__ beo1,
    const float* __restrict__ beo2, const float* __restrict__ Watt,
    const float* __restrict__ batt,
    unsigned int* __restrict__ edge_out, float* __restrict__ e4_out,
    float* __restrict__ dir_out)
{
  __shared__ __align__(16) unsigned char sR1[128*264];   // 33792 B
  __shared__ __align__(16) unsigned char sR2[128*144];   // 18432 B
  __shared__ float sdv[128];
  __shared__ float semd[128];

  const int tid  = threadIdx.x;
  const int wv   = tid >> 6;
  const int lane = tid & 63;
  const int l15  = lane & 15;
  const int quad = lane >> 4;
  const int pbase = blockIdx.x * 128;

  if (lane < 32){
    int row = 32*wv + lane;
    int p2 = pbase + row;
    int ii = idx_i[p2], jj = idx_j[p2];
    float xi0=x[ii*3], xi1=x[ii*3+1], xi2=x[ii*3+2];
    float xj0=x[jj*3], xj1=x[jj*3+1], xj2=x[jj*3+2];
    float rx=xj0-xi0, ry=xj1-xi1, rz=xj2-xi2;
    float d = sqrtf(rx*rx+ry*ry+rz*rz+EPSF);
    float iv = 1.0f/(d+EPSF);
    sdv[row] = d;
    semd[row] = __expf(-d);
    *(float4*)(dir_out + (size_t)p2*4) = make_float4(rx*iv, ry*iv, rz*iv, d);
  }

  {
    int rr = lane >> 1;
    int row = 32*wv + rr;
    int p1 = pbase + row;
    int hidx = (lane & 1) ? idx_j[p1] : idx_i[p1];
    const float4* hp = (const float4*)(h + (size_t)hidx*64);
    unsigned char* dst = sR1 + row*264 + (lane&1)*128;
    #pragma unroll
    for (int q=0;q<8;q++){
      float4 a = hp[2*q], b = hp[2*q+1];
      uint4 o = make_uint4(pack2(a.x,a.y), pack2(a.z,a.w), pack2(b.x,b.y), pack2(b.z,b.w));
      *(uint4*)(dst + q*16) = o;
    }
  }

  f32x4 acc[2][8];
  #pragma unroll
  for (int mf=0; mf<2; mf++)
    #pragma unroll
    for (int nf=0; nf<8; nf++){
      float bias;
      if (nf < 4){ int nn = 16*nf + l15; bias = (nn < 50) ? bein[nn] : 0.f; }
      else       { bias = beo1[16*(nf-4) + l15]; }
      acc[mf][nf] = (f32x4){bias, bias, bias, bias};
    }
  #pragma unroll
  for (int s=0; s<4; s++){
    int koff = s*32 + quad*8;
    short8 a0 = ld_frag(sR1 + (32*wv + l15)*264      + koff*2);
    short8 a1 = ld_frag(sR1 + (32*wv + 16 + l15)*264 + koff*2);
    #pragma unroll
    for (int nf=0; nf<8; nf++){
      short8 b = ld_frag((const unsigned char*)wb1 + (16*nf + l15)*256 + koff*2);
      acc[0][nf] = mfma16(a0, b, acc[0][nf]);
      acc[1][nf] = mfma16(a1, b, acc[1][nf]);
    }
  }

  #pragma unroll
  for (int mf=0; mf<2; mf++)
    #pragma unroll
    for (int nf=0; nf<4; nf++){
      int n = 16*nf + l15;
      float mu = MU0F + (float)n*DMUF;
      #pragma unroll
      for (int reg=0; reg<4; reg++){
        int row = 32*wv + 16*mf + quad*4 + reg;
        float t = semd[row] - mu;
        float fv = acc[mf][nf][reg] * __expf(-BETAF*t*t);
        unsigned short ob;
        if (n < 50)       ob = (unsigned short)f2b16(fv);
        else if (n == 50) ob = (unsigned short)f2b16(sdv[row]);
        else              ob = 0;
        ((unsigned short*)sR2)[row*72 + n] = ob;
      }
    }

  #pragma unroll
  for (int s=0; s<2; s++){
    int koff = s*32 + quad*8;
    short8 a0 = ld_frag(sR2 + (32*wv + l15)*144      + koff*2);
    short8 a1 = ld_frag(sR2 + (32*wv + 16 + l15)*144 + koff*2);
    #pragma unroll
    for (int nf=0; nf<4; nf++){
      short8 b = ld_frag((const unsigned char*)wb2 + (16*nf + l15)*128 + koff*2);
      acc[0][4+nf] = mfma16(a0, b, acc[0][4+nf]);
      acc[1][4+nf] = mfma16(a1, b, acc[1][4+nf]);
    }
  }

  unsigned char* A3 = sR1 + 8448*wv;
  #pragma unroll
  for (int mf=0; mf<2; mf++)
    #pragma unroll
    for (int nf=0; nf<4; nf++){
      int n = 16*nf + l15;
      #pragma unroll
      for (int reg=0; reg<4; reg++){
        int rr = 16*mf + quad*4 + reg;
        ((unsigned short*)A3)[rr*72 + n] = (unsigned short)f2b16(silu_f(acc[mf][4+nf][reg]));
      }
    }

  f32x4 acc3[2][2];
  #pragma unroll
  for (int mf=0; mf<2; mf++)
    #pragma unroll
    for (int nf=0; nf<2; nf++){
      float bias = beo2[16*nf + l15];
      acc3[mf][nf] = (f32x4){bias, bias, bias, bias};
    }
  #pragma unroll
  for (int s=0; s<2; s++){
    int koff = s*32 + quad*8;
    short8 a0 = ld_frag(A3 + (l15)*144      + koff*2);
    short8 a1 = ld_frag(A3 + (16 + l15)*144 + koff*2);
    #pragma unroll
    for (int nf=0; nf<2; nf++){
      short8 b = ld_frag((const unsigned char*)wb3 + (16*nf + l15)*128 + koff*2);
      acc3[0][nf] = mfma16(a0, b, acc3[0][nf]);
      acc3[1][nf] = mfma16(a1, b, acc3[1][nf]);
    }
  }

  #pragma unroll
  for (int mf=0; mf<2; mf++)
    #pragma unroll
    for (int nf=0; nf<2; nf++){
      int n = 16*nf + l15;
      #pragma unroll
      for (int reg=0; reg<4; reg++){
        int row = 32*wv + 16*mf + quad*4 + reg;
        ((float*)sR2)[row*36 + n] = acc3[mf][nf][reg];
      }
    }

  {
    int rr = lane >> 1;
    int row = 32*wv + rr;
    int p = pbase + row;
    int cb = (lane & 1) * 16;
    const float* er = (const float*)sR2 + row*36;
    float l0, l1, l2, l3;
    if ((lane & 1) == 0){ l0 = batt[0]; l1 = batt[1]; l2 = batt[2]; l3 = batt[3]; }
    else                { l0 = l1 = l2 = l3 = 0.f; }
    float ecache[16];
    #pragma unroll
    for (int c=0;c<16;c++){
      float ev = er[cb + c];
      ecache[c] = ev;
      const float4 wr = *(const float4*)(Watt + (cb + c)*4);
      l0 += ev*wr.x; l1 += ev*wr.y; l2 += ev*wr.z; l3 += ev*wr.w;
    }
    l0 += __shfl_xor(l0,1); l1 += __shfl_xor(l1,1);
    l2 += __shfl_xor(l2,1); l3 += __shfl_xor(l3,1);
    if ((lane & 1) == 0){
      float e0 = __expf(l0 > 0.f ? l0 : 2.f*(__expf(l0*0.5f)-1.f));
      float e1 = __expf(l1 > 0.f ? l1 : 2.f*(__expf(l1*0.5f)-1.f));
      float e2 = __expf(l2 > 0.f ? l2 : 2.f*(__expf(l2*0.5f)-1.f));
      float e3 = __expf(l3 > 0.f ? l3 : 2.f*(__expf(l3*0.5f)-1.f));
      *(float4*)(e4_out + (size_t)p*4) = make_float4(e0, e1, e2, e3);
    }
    uint4 o1 = make_uint4(pack2(ecache[0],ecache[1]),  pack2(ecache[2],ecache[3]),
                          pack2(ecache[4],ecache[5]),  pack2(ecache[6],ecache[7]));
    uint4 o2 = make_uint4(pack2(ecache[8],ecache[9]),  pack2(ecache[10],ecache[11]),
                          pack2(ecache[12],ecache[13]),pack2(ecache[14],ecache[15]));
    unsigned int* ep = edge_out + (size_t)p*16 + (lane&1)*8;
    *(uint4*)(ep)     = o1;
    *(uint4*)(ep + 4) = o2;
  }
}

// ---------------- node kernel: 4 waves/block, 1 node/wave, MFMA g ----------------
// Per-wave LDS (10112 B): gC [32 rows][264 B] (8448; first 2048 B double as the
// A-staging region for the 32-pair edge tile) | sIn[256] | sN2[32] | sT[64] | sT2[64].
// No barriers: all LDS traffic is wave-local (in-order DS per wave).
__global__ __launch_bounds__(256, 2) void k_node4(
    const float* __restrict__ h,
    const float* __restrict__ x,
    const float* __restrict__ v,
    const int* __restrict__ offsets,
    const int* __restrict__ sorted,
    const unsigned int* __restrict__ edgeb,
    const float* __restrict__ e4,
    const float* __restrict__ dir4,
    const unsigned short* __restrict__ wb4,
    const float* __restrict__ Wvm,
    const float* __restrict__ Wpn1, const float* __restrict__ bpn1,
    const float* __restrict__ Wpn2, const float* __restrict__ bpn2,
    const float* __restrict__ Wn1,  const float* __restrict__ bn1,
    const float* __restrict__ Wn2,  const float* __restrict__ bn2,
    const float* __restrict__ Wv1,  const float* __restrict__ bv1,
    const float* __restrict__ Wv2,
    float* __restrict__ out)
{
  __shared__ __align__(16) unsigned char sAllB[4*10112];
  const int wv   = threadIdx.x >> 6;
  const int lane = threadIdx.x & 63;
  unsigned char* gC = sAllB + wv*10112;
  float* sIn = (float*)(gC + 8448);
  float* sN2 = sIn + 256;
  float* sT  = sN2 + 32;
  float* sT2 = sT + 64;

  const int i = blockIdx.x*4 + wv;
  const int n0 = offsets[i], n1 = offsets[i+1];
  const int cnt = n1 - n0;
  const int c    = lane & 31;
  const int l15  = lane & 15;
  const int quad = lane >> 4;
  const bool low = (lane < 32);

  // preload Wxm^T B-fragments (8 n-frags, K=32) into registers
  short8 b4[8];
  #pragma unroll
  for (int nf=0; nf<8; nf++)
    b4[nf] = ld_frag((const unsigned char*)wb4 + (16*nf + l15)*64 + quad*16);
  const float wvm_c = Wvm[c];

  // pass A: softmax denominators per head
  float d0=0.f,d1=0.f,d2=0.f,d3=0.f;
  for (int s = n0 + lane; s < n1; s += 64){
    int p = sorted[s];
    const float4 ev = *(const float4*)(e4 + (size_t)p*4);
    d0+=ev.x; d1+=ev.y; d2+=ev.z; d3+=ev.w;
  }
  #pragma unroll
  for (int off=32; off>=1; off>>=1){
    d0 += __shfl_xor(d0,off); d1 += __shfl_xor(d1,off);
    d2 += __shfl_xor(d2,off); d3 += __shfl_xor(d3,off);
  }
  const float i0 = (cnt>0)?1.f/d0:0.f, i1 = (cnt>0)?1.f/d1:0.f;
  const float i2 = (cnt>0)?1.f/d2:0.f, i3 = (cnt>0)?1.f/d3:0.f;

  float sem4[4] = {0.f,0.f,0.f,0.f};
  float cx=0.f,cy=0.f,cz=0.f, gx=0.f,gy=0.f,gz=0.f;

  // chunked main loop: 32 pairs per MFMA tile
  for (int base = n0; base < n1; base += 32){
    const int nc = min(32, n1 - base);
    // stage A: edge rows (bf16 [row][32]) into gC[0:2048)
    {
      int rr = lane >> 1, hf = lane & 1;
      if (rr < nc){
        int p = sorted[base + rr];
        const uint4* src = (const uint4*)(edgeb + (size_t)p*16 + hf*8);
        uint4 u0 = src[0], u1 = src[1];
        *(uint4*)(gC + rr*64 + hf*32)      = u0;
        *(uint4*)(gC + rr*64 + hf*32 + 16) = u1;
      }
    }
    // GEMM: g[32 pairs][128 n] = A[32][32] @ Wxm^T[32][128]
    short8 a0 = ld_frag(gC + l15*64 + quad*16);
    short8 a1 = ld_frag(gC + (16+l15)*64 + quad*16);
    f32x4 accg[2][8];
    #pragma unroll
    for (int nf=0; nf<8; nf++){
      f32x4 z = (f32x4){0.f,0.f,0.f,0.f};
      accg[0][nf] = mfma16(a0, b4[nf], z);
      accg[1][nf] = mfma16(a1, b4[nf], z);
    }
    // C -> LDS bf16 [row][132 ushort] (264 B rows; overlays dead A region)
    #pragma unroll
    for (int mf=0; mf<2; mf++)
      #pragma unroll
      for (int nf=0; nf<8; nf++){
        int n = 16*nf + l15;
        #pragma unroll
        for (int reg=0; reg<4; reg++){
          int row = 16*mf + quad*4 + reg;
          ((unsigned short*)gC)[row*132 + n] = (unsigned short)f2b16(accg[mf][nf][reg]);
        }
      }
    // inner: 2 pairs per iteration (one per half-wave)
    for (int t0 = 0; t0 < nc; t0 += 2){
      const int rloc = t0 + (lane >> 5);
      const bool act = rloc < nc;
      const int prd = sorted[base + (act ? rloc : 0)];
      const float4 ev = *(const float4*)(e4 + (size_t)prd*4);
      const float4 dv = *(const float4*)(dir4 + (size_t)prd*4);
      const float aw0 = ev.x*i0, aw1 = ev.y*i1, aw2 = ev.z*i2, aw3 = ev.w*i3;
      uint2 gv = *(const uint2*)(gC + rloc*264 + c*8);
      float g0=u2f(gv.x<<16), g1=u2f(gv.x&0xffff0000u);
      float g2=u2f(gv.y<<16), g3=u2f(gv.y&0xffff0000u);
      float tp = aw0*g0 + aw1*g1 + aw2*g2 + aw3*g3;
      float tt = fminf(fmaxf(tp, -15.f), 15.f);
      float ex = __expf(2.f*tt);
      float th = (ex-1.f)/(ex+1.f);
      unsigned int ew = edgeb[(size_t)prd*16 + (c>>1)];
      float ec = (c & 1) ? u2f(ew & 0xffff0000u) : u2f(ew << 16);
      if (act){
        sem4[0] += ec*aw0; sem4[1] += ec*aw1;
        sem4[2] += ec*aw2; sem4[3] += ec*aw3;
        cx += th*dv.x; cy += th*dv.y; cz += th*dv.z;
        float tw = th*wvm_c;
        gx += tw*dv.x; gy += tw*dv.y; gz += tw*dv.z;
      }
    }
  }

  // cross-half combine (each half handled disjoint pairs)
  #pragma unroll
  for (int j=0;j<4;j++) sem4[j] += __shfl_xor(sem4[j], 32);
  cx += __shfl_xor(cx,32); cy += __shfl_xor(cy,32); cz += __shfl_xor(cz,32);
  #pragma unroll
  for (int off=32; off>=1; off>>=1){
    gx += __shfl_xor(gx,off); gy += __shfl_xor(gy,off); gz += __shfl_xor(gz,off);
  }
  const float invc = 1.f/(float)(cnt > 1 ? cnt : 1);
  const float dvx = gx*invc, dvy = gy*invc, dvz = gz*invc;

  if (low){
    float mx = cx*invc, my = cy*invc, mz = cz*invc;
    sN2[c] = mx*mx + my*my + mz*mz;
    *(float4*)(sIn + 64 + 4*c) = make_float4(sem4[0], sem4[1], sem4[2], sem4[3]);
  }
  sIn[lane] = h[(size_t)i*64 + lane];

  // spatial MLP: 32 -> 64 -> 64
  float s1 = bpn1[lane];
  #pragma unroll
  for (int cc=0;cc<32;cc++) s1 += sN2[cc]*Wpn1[cc*64+lane];
  s1 = silu_f(s1);
  sT[lane] = s1;
  float s2 = bpn2[lane];
  for (int o=0;o<64;o+=4){
    const float4 t4 = *(const float4*)(&sT[o]);
    s2 += t4.x*Wpn2[o*64+lane] + t4.y*Wpn2[(o+1)*64+lane]
        + t4.z*Wpn2[(o+2)*64+lane] + t4.w*Wpn2[(o+3)*64+lane];
  }
  sIn[192+lane] = silu_f(s2);

  // node MLP: 256 -> 64 -> 64, residual
  float b1 = bn1[lane];
  for (int m=0;m<256;m+=4){
    const float4 t4 = *(const float4*)(&sIn[m]);
    b1 += t4.x*Wn1[m*64+lane] + t4.y*Wn1[(m+1)*64+lane]
        + t4.z*Wn1[(m+2)*64+lane] + t4.w*Wn1[(m+3)*64+lane];
  }
  b1 = silu_f(b1);
  sT[lane] = b1;
  float b2 = bn2[lane];
  for (int m=0;m<64;m+=4){
    const float4 t4 = *(const float4*)(&sT[m]);
    b2 += t4.x*Wn2[m*64+lane] + t4.y*Wn2[(m+1)*64+lane]
        + t4.z*Wn2[(m+2)*64+lane] + t4.w*Wn2[(m+3)*64+lane];
  }
  const float hnew = sIn[lane] + silu_f(b2);
  out[(size_t)i*64 + lane] = hnew;
  sT2[lane] = hnew;

  // velocity gate: 64 -> 64 -> 1
  float c1 = bv1[lane];
  for (int m=0;m<64;m+=4){
    const float4 t4 = *(const float4*)(&sT2[m]);
    c1 += t4.x*Wv1[m*64+lane] + t4.y*Wv1[(m+1)*64+lane]
        + t4.z*Wv1[(m+2)*64+lane] + t4.w*Wv1[(m+3)*64+lane];
  }
  c1 = silu_f(c1);
  float gp = c1 * Wv2[lane];
  #pragma unroll
  for (int off=32; off>=1; off>>=1) gp += __shfl_xor(gp, off);
  const float gate = 2.f/(1.f + __expf(-gp));

  if (lane < 3){
    float vv = v[(size_t)i*3 + lane];
    float xx = x[(size_t)i*3 + lane];
    float ds = (lane==0) ? dvx : ((lane==1) ? dvy : dvz);
    float vn = gate*vv + ds;
    out[(size_t)N_*64 + (size_t)i*3 + lane]                 = xx + vn;
    out[(size_t)N_*64 + (size_t)N_*3 + (size_t)i*3 + lane]  = vn;
  }
}

// ---------------- launch ----------------
extern "C" void kernel_launch(void* const* d_in, const int* in_sizes, int n_in,
                              void* d_out, int out_size, void* d_ws, size_t ws_size,
                              hipStream_t stream)
{
  const float* h = (const float*)d_in[0];
  const float* x = (const float*)d_in[1];
  const float* v = (const float*)d_in[2];
  const int* idx_i = (const int*)d_in[3];
  const int* idx_j = (const int*)d_in[4];
  const float* Wein = (const float*)d_in[5];  const float* bein = (const float*)d_in[6];
  const float* Weo1 = (const float*)d_in[7];  const float* beo1 = (const float*)d_in[8];
  const float* Weo2 = (const float*)d_in[9];  const float* beo2 = (const float*)d_in[10];
  const float* Watt = (const float*)d_in[11]; const float* batt = (const float*)d_in[12];
  const float* Wxm  = (const float*)d_in[13]; const float* Wvm  = (const float*)d_in[14];
  const float* Wpn1 = (const float*)d_in[15]; const float* bpn1 = (const float*)d_in[16];
  const float* Wpn2 = (const float*)d_in[17]; const float* bpn2 = (const float*)d_in[18];
  const float* Wn1  = (const float*)d_in[19]; const float* bn1  = (const float*)d_in[20];
  const float* Wn2  = (const float*)d_in[21]; const float* bn2  = (const float*)d_in[22];
  const float* Wv1  = (const float*)d_in[23]; const float* bv1  = (const float*)d_in[24];
  const float* Wv2  = (const float*)d_in[25];

  float* wsf        = (float*)d_ws;
  int*   cnt        = (int*)(wsf + OFF_CNT);
  int*   offsets    = (int*)(wsf + OFF_OFFSETS);
  int*   cursor     = (int*)(wsf + OFF_CURSOR);
  int*   sorted     = (int*)(wsf + OFF_SORTED);
  unsigned int* edgeb = (unsigned int*)(wsf + OFF_EDGE);
  float* e4o        = wsf + OFF_E4;
  float* diro       = wsf + OFF_DIR;
  unsigned short* wb1 = (unsigned short*)(wsf + OFF_WB1);
  unsigned short* wb2 = (unsigned short*)(wsf + OFF_WB2);
  unsigned short* wb3 = (unsigned short*)(wsf + OFF_WB3);
  unsigned short* wb4 = (unsigned short*)(wsf + OFF_WB4);

  hipMemsetAsync(cnt, 0, N_*sizeof(int), stream);
  k_hist<<<(P_+255)/256, 256, 0, stream>>>(idx_i, cnt);
  k_scan<<<1, 1024, 0, stream>>>(cnt, offsets, cursor);
  // cnt dead after scan -> overlay transposed weights there
  k_prepw<<<32, 256, 0, stream>>>(Wein, Weo1, Weo2, Wxm, wb1, wb2, wb3, wb4);
  k_scatter<<<(P_+255)/256, 256, 0, stream>>>(idx_i, cursor, sorted);
  k_edge2<<<P_/128, 256, 0, stream>>>(h, x, idx_i, idx_j, wb1, wb2, wb3,
                                      bein, beo1, beo2, Watt, batt,
                                      edgeb, e4o, diro);
  k_node4<<<N_/4, 256, 0, stream>>>(h, x, v, offsets, sorted, edgeb, e4o, diro,
                                    wb4, Wvm, Wpn1, bpn1, Wpn2, bpn2,
                                    Wn1, bn1, Wn2, bn2, Wv1, bv1, Wv2,
                                    (float*)d_out);
}

// Round 5
// 451.754 us; speedup vs baseline: 2.4013x; 1.0152x over previous
//
#include <hip/hip_runtime.h>
#include <hip/hip_bf16.h>

#define DEV __device__ __forceinline__

constexpr int N_ = 25000;
constexpr int P_ = 400000;

// ---------------- ws layout (units of 4 bytes) ----------------
constexpr int align4(int xx){ return (xx+3)&~3; }
constexpr int OFF_CNT     = 0;                          // N ints (dead after k_scan)
constexpr int OFF_OFFSETS = align4(OFF_CNT + N_);       // N+1 ints
constexpr int OFF_CURSOR  = align4(OFF_OFFSETS + N_ + 1);
constexpr int OFF_SORTED  = align4(OFF_CURSOR + N_);    // P ints
constexpr int OFF_EDGE    = align4(OFF_SORTED + P_);    // P*16 dwords (32 bf16 edge feats, sorted order)
constexpr int OFF_E4      = OFF_EDGE + P_*16;           // P*4  f32 (exp(att) per head, sorted order)
constexpr int OFF_DIR     = OFF_E4 + P_*4;              // P*4  f32 (x,y,z,d, sorted order)
constexpr int WS_UNITS    = OFF_DIR + P_*4;             // ~10.1M dwords = 41 MB

// transposed bf16 weights overlaid on the dead cnt region (13312 dw <= 25000 dw)
constexpr int OFF_WB1 = OFF_CNT;          // [128 n][128 k] bf16 = 8192 dw
constexpr int OFF_WB2 = OFF_WB1 + 8192;   // [64 n][64 k]  bf16 = 2048 dw
constexpr int OFF_WB3 = OFF_WB2 + 2048;   // [32 n][64 k]  bf16 = 1024 dw
constexpr int OFF_WB4 = OFF_WB3 + 1024;   // [128 n][32 k] bf16 = 2048 dw (Wxm^T, n=4c+h)

// PhysNet RBF constants (K=50, r_max=0.5)
constexpr float MU0F  = 0.60653065971263342f;               // exp(-0.5)
constexpr float DMUF  = (1.0f - 0.60653065971263342f) / 49.0f;
constexpr float BETAF = 1.0f / ((0.04f * (1.0f - 0.60653065971263342f)) *
                                (0.04f * (1.0f - 0.60653065971263342f)));
constexpr float EPSF  = 1e-8f;

DEV float u2f(unsigned int u){ union{unsigned int i; float f;} c; c.i=u; return c.f; }
DEV unsigned int f2b16(float f){
  __hip_bfloat16 b = __float2bfloat16(f);
  unsigned short s; __builtin_memcpy(&s, &b, 2);
  return (unsigned int)s;
}
DEV unsigned int pack2(float a, float b){ return f2b16(a) | (f2b16(b) << 16); }
DEV float silu_f(float v){ return v / (1.0f + __expf(-v)); }

using short8 = __attribute__((ext_vector_type(8))) short;   // 8 bf16 (4 VGPRs)
using f32x4  = __attribute__((ext_vector_type(4))) float;
union U4S8 { uint4 u; short8 s; };
DEV short8 ld_frag(const void* p){ U4S8 c; c.u = *(const uint4*)p; return c.s; }
DEV f32x4 mfma16(short8 a, short8 b, f32x4 c){
  return __builtin_amdgcn_mfma_f32_16x16x32_bf16(a, b, c, 0, 0, 0);
}

// ---------------- counting sort by idx_i ----------------
__global__ void k_hist(const int* __restrict__ idx_i, int* __restrict__ cnt){
  int t = blockIdx.x*256 + threadIdx.x;
  if (t < P_) atomicAdd(&cnt[idx_i[t]], 1);
}

// 2-barrier scan (shfl wave-scan + cross-wave combine)
__global__ __launch_bounds__(1024) void k_scan(const int* __restrict__ cnt,
                                               int* __restrict__ offsets,
                                               int* __restrict__ cursor){
  __shared__ int swv[16];
  const int t = threadIdx.x;
  const int wv = t >> 6, ln = t & 63;
  constexpr int CH = (N_ + 1023)/1024;   // 25
  int b = t*CH, e = b+CH;
  if (b > N_) b = N_;
  if (e > N_) e = N_;
  int s = 0;
  for (int q=b; q<e; q++) s += cnt[q];
  int incl = s;
  #pragma unroll
  for (int off=1; off<64; off<<=1){
    int vv = __shfl_up(incl, off);
    if (ln >= off) incl += vv;
  }
  if (ln == 63) swv[wv] = incl;
  __syncthreads();
  if (wv == 0 && ln < 16){
    int w = swv[ln];
    #pragma unroll
    for (int off=1; off<16; off<<=1){
      int vv = __shfl_up(w, off);
      if (ln >= off) w += vv;
    }
    swv[ln] = w;
  }
  __syncthreads();
  const int wpre = (wv > 0) ? swv[wv-1] : 0;
  int run = wpre + incl - s;                 // exclusive prefix for this thread
  for (int q=b; q<e; q++){ offsets[q] = run; cursor[q] = run; run += cnt[q]; }
  if (t == 1023) offsets[N_] = run;          // run == grand total here
}

__global__ void k_scatter(const int* __restrict__ idx_i, int* __restrict__ cursor,
                          int* __restrict__ sorted){
  int t = blockIdx.x*256 + threadIdx.x;
  if (t < P_){ int pos = atomicAdd(&cursor[idx_i[t]], 1); sorted[pos] = t; }
}

// ---------------- weight transpose/convert to bf16 [N][K] ----------------
__global__ void k_prepw(const float* __restrict__ Wein, const float* __restrict__ Weo1,
                        const float* __restrict__ Weo2, const float* __restrict__ Wxm,
                        unsigned short* __restrict__ wb1, unsigned short* __restrict__ wb2,
                        unsigned short* __restrict__ wb3, unsigned short* __restrict__ wb4){
  int t = blockIdx.x*256 + threadIdx.x, st = gridDim.x*256;
  for (int q=t; q<128*128; q+=st){
    int n=q>>7, k=q&127;
    float v = (n<50) ? Wein[k*50+n] : ((n<64) ? 0.f : Weo1[k*64+(n-64)]);
    wb1[q] = (unsigned short)f2b16(v);
  }
  for (int q=t; q<64*64; q+=st){
    int n=q>>6, k=q&63;
    float v = (k<50) ? Weo1[(128+k)*64+n] : ((k==50) ? Weo1[178*64+n] : 0.f);
    wb2[q] = (unsigned short)f2b16(v);
  }
  for (int q=t; q<32*64; q+=st){
    int n=q>>6, k=q&63;
    wb3[q] = (unsigned short)f2b16(Weo2[k*32+n]);
  }
  // wb4[n][k] with n = 4c+h, k = e:  Wxm[e*4+h, c]
  for (int q=t; q<128*32; q+=st){
    int n=q>>5, k=q&31;
    int cc = n>>2, hh = n&3;
    wb4[q] = (unsigned short)f2b16(Wxm[(k*4+hh)*32 + cc]);
  }
}

// ---------------- MFMA edge kernel: processes pairs in SORTED order ----------------
// Tile position p' handles pair sorted[p']; all outputs written at p' (contiguous
// for the node kernel). i-side h rows are L1-local (sorted groups by receiver).
__global__ __launch_bounds__(256, 3) void k_edge2(
    const float* __restrict__ h, const float* __restrict__ x,
    const int* __restrict__ idx_i, const int* __restrict__ idx_j,
    const int* __restrict__ sorted,
    const unsigned short* __restrict__ wb1, const unsigned short* __restrict__ wb2,
    const unsigned short* __restrict__ wb3,
    const float* __restrict__ bein, const float* __restrict__ beo1,
    const float* __restrict__ beo2, const float* __restrict__ Watt,
    const float* __restrict__ batt,
    unsigned int* __restrict__ edge_out, float* __restrict__ e4_out,
    float* __restrict__ dir_out)
{
  __shared__ __align__(16) unsigned char sR1[128*264];   // 33792 B
  __shared__ __align__(16) unsigned char sR2[128*144];   // 18432 B
  __shared__ float sdv[128];
  __shared__ float semd[128];

  const int tid  = threadIdx.x;
  const int wv   = tid >> 6;
  const int lane = tid & 63;
  const int l15  = lane & 15;
  const int quad = lane >> 4;
  const int pbase = blockIdx.x * 128;

  if (lane < 32){
    int row = 32*wv + lane;
    int p2 = pbase + row;
    int pp = sorted[p2];
    int ii = idx_i[pp], jj = idx_j[pp];
    float xi0=x[ii*3], xi1=x[ii*3+1], xi2=x[ii*3+2];
    float xj0=x[jj*3], xj1=x[jj*3+1], xj2=x[jj*3+2];
    float rx=xj0-xi0, ry=xj1-xi1, rz=xj2-xi2;
    float d = sqrtf(rx*rx+ry*ry+rz*rz+EPSF);
    float iv = 1.0f/(d+EPSF);
    sdv[row] = d;
    semd[row] = __expf(-d);
    *(float4*)(dir_out + (size_t)p2*4) = make_float4(rx*iv, ry*iv, rz*iv, d);
  }

  {
    int rr = lane >> 1;
    int row = 32*wv + rr;
    int pp1 = sorted[pbase + row];
    int hidx = (lane & 1) ? idx_j[pp1] : idx_i[pp1];
    const float4* hp = (const float4*)(h + (size_t)hidx*64);
    unsigned char* dst = sR1 + row*264 + (lane&1)*128;
    #pragma unroll
    for (int q=0;q<8;q++){
      float4 a = hp[2*q], b = hp[2*q+1];
      uint4 o = make_uint4(pack2(a.x,a.y), pack2(a.z,a.w), pack2(b.x,b.y), pack2(b.z,b.w));
      *(uint4*)(dst + q*16) = o;
    }
  }

  f32x4 acc[2][8];
  #pragma unroll
  for (int mf=0; mf<2; mf++)
    #pragma unroll
    for (int nf=0; nf<8; nf++){
      float bias;
      if (nf < 4){ int nn = 16*nf + l15; bias = (nn < 50) ? bein[nn] : 0.f; }
      else       { bias = beo1[16*(nf-4) + l15]; }
      acc[mf][nf] = (f32x4){bias, bias, bias, bias};
    }
  #pragma unroll
  for (int s=0; s<4; s++){
    int koff = s*32 + quad*8;
    short8 a0 = ld_frag(sR1 + (32*wv + l15)*264      + koff*2);
    short8 a1 = ld_frag(sR1 + (32*wv + 16 + l15)*264 + koff*2);
    #pragma unroll
    for (int nf=0; nf<8; nf++){
      short8 b = ld_frag((const unsigned char*)wb1 + (16*nf + l15)*256 + koff*2);
      acc[0][nf] = mfma16(a0, b, acc[0][nf]);
      acc[1][nf] = mfma16(a1, b, acc[1][nf]);
    }
  }

  #pragma unroll
  for (int mf=0; mf<2; mf++)
    #pragma unroll
    for (int nf=0; nf<4; nf++){
      int n = 16*nf + l15;
      float mu = MU0F + (float)n*DMUF;
      #pragma unroll
      for (int reg=0; reg<4; reg++){
        int row = 32*wv + 16*mf + quad*4 + reg;
        float t = semd[row] - mu;
        float fv = acc[mf][nf][reg] * __expf(-BETAF*t*t);
        unsigned short ob;
        if (n < 50)       ob = (unsigned short)f2b16(fv);
        else if (n == 50) ob = (unsigned short)f2b16(sdv[row]);
        else              ob = 0;
        ((unsigned short*)sR2)[row*72 + n] = ob;
      }
    }

  #pragma unroll
  for (int s=0; s<2; s++){
    int koff = s*32 + quad*8;
    short8 a0 = ld_frag(sR2 + (32*wv + l15)*144      + koff*2);
    short8 a1 = ld_frag(sR2 + (32*wv + 16 + l15)*144 + koff*2);
    #pragma unroll
    for (int nf=0; nf<4; nf++){
      short8 b = ld_frag((const unsigned char*)wb2 + (16*nf + l15)*128 + koff*2);
      acc[0][4+nf] = mfma16(a0, b, acc[0][4+nf]);
      acc[1][4+nf] = mfma16(a1, b, acc[1][4+nf]);
    }
  }

  unsigned char* A3 = sR1 + 8448*wv;
  #pragma unroll
  for (int mf=0; mf<2; mf++)
    #pragma unroll
    for (int nf=0; nf<4; nf++){
      int n = 16*nf + l15;
      #pragma unroll
      for (int reg=0; reg<4; reg++){
        int rr = 16*mf + quad*4 + reg;
        ((unsigned short*)A3)[rr*72 + n] = (unsigned short)f2b16(silu_f(acc[mf][4+nf][reg]));
      }
    }

  f32x4 acc3[2][2];
  #pragma unroll
  for (int mf=0; mf<2; mf++)
    #pragma unroll
    for (int nf=0; nf<2; nf++){
      float bias = beo2[16*nf + l15];
      acc3[mf][nf] = (f32x4){bias, bias, bias, bias};
    }
  #pragma unroll
  for (int s=0; s<2; s++){
    int koff = s*32 + quad*8;
    short8 a0 = ld_frag(A3 + (l15)*144      + koff*2);
    short8 a1 = ld_frag(A3 + (16 + l15)*144 + koff*2);
    #pragma unroll
    for (int nf=0; nf<2; nf++){
      short8 b = ld_frag((const unsigned char*)wb3 + (16*nf + l15)*128 + koff*2);
      acc3[0][nf] = mfma16(a0, b, acc3[0][nf]);
      acc3[1][nf] = mfma16(a1, b, acc3[1][nf]);
    }
  }

  #pragma unroll
  for (int mf=0; mf<2; mf++)
    #pragma unroll
    for (int nf=0; nf<2; nf++){
      int n = 16*nf + l15;
      #pragma unroll
      for (int reg=0; reg<4; reg++){
        int row = 32*wv + 16*mf + quad*4 + reg;
        ((float*)sR2)[row*36 + n] = acc3[mf][nf][reg];
      }
    }

  {
    int rr = lane >> 1;
    int row = 32*wv + rr;
    int p = pbase + row;
    int cb = (lane & 1) * 16;
    const float* er = (const float*)sR2 + row*36;
    float l0, l1, l2, l3;
    if ((lane & 1) == 0){ l0 = batt[0]; l1 = batt[1]; l2 = batt[2]; l3 = batt[3]; }
    else                { l0 = l1 = l2 = l3 = 0.f; }
    float ecache[16];
    #pragma unroll
    for (int c=0;c<16;c++){
      float ev = er[cb + c];
      ecache[c] = ev;
      const float4 wr = *(const float4*)(Watt + (cb + c)*4);
      l0 += ev*wr.x; l1 += ev*wr.y; l2 += ev*wr.z; l3 += ev*wr.w;
    }
    l0 += __shfl_xor(l0,1); l1 += __shfl_xor(l1,1);
    l2 += __shfl_xor(l2,1); l3 += __shfl_xor(l3,1);
    if ((lane & 1) == 0){
      float e0 = __expf(l0 > 0.f ? l0 : 2.f*(__expf(l0*0.5f)-1.f));
      float e1 = __expf(l1 > 0.f ? l1 : 2.f*(__expf(l1*0.5f)-1.f));
      float e2 = __expf(l2 > 0.f ? l2 : 2.f*(__expf(l2*0.5f)-1.f));
      float e3 = __expf(l3 > 0.f ? l3 : 2.f*(__expf(l3*0.5f)-1.f));
      *(float4*)(e4_out + (size_t)p*4) = make_float4(e0, e1, e2, e3);
    }
    uint4 o1 = make_uint4(pack2(ecache[0],ecache[1]),  pack2(ecache[2],ecache[3]),
                          pack2(ecache[4],ecache[5]),  pack2(ecache[6],ecache[7]));
    uint4 o2 = make_uint4(pack2(ecache[8],ecache[9]),  pack2(ecache[10],ecache[11]),
                          pack2(ecache[12],ecache[13]),pack2(ecache[14],ecache[15]));
    unsigned int* ep = edge_out + (size_t)p*16 + (lane&1)*8;
    *(uint4*)(ep)     = o1;
    *(uint4*)(ep + 4) = o2;
  }
}

// ---------------- node kernel: 4 waves/block, 1 node/wave, contiguous streams ----------
// Per-wave LDS (10496 B): sA edge tile [32 rows][64 B] (2048) | gC [32 rows][264 B]
// (8448). MLP scratch overlays sA after the chunk loop. No barriers (wave-local LDS).
__global__ __launch_bounds__(256, 3) void k_node4(
    const float* __restrict__ h,
    const float* __restrict__ x,
    const float* __restrict__ v,
    const int* __restrict__ offsets,
    const unsigned int* __restrict__ edgeb,   // sorted order
    const float* __restrict__ e4,             // sorted order
    const float* __restrict__ dir4,           // sorted order
    const unsigned short* __restrict__ wb4,
    const float* __restrict__ Wvm,
    const float* __restrict__ Wpn1, const float* __restrict__ bpn1,
    const float* __restrict__ Wpn2, const float* __restrict__ bpn2,
    const float* __restrict__ Wn1,  const float* __restrict__ bn1,
    const float* __restrict__ Wn2,  const float* __restrict__ bn2,
    const float* __restrict__ Wv1,  const float* __restrict__ bv1,
    const float* __restrict__ Wv2,
    float* __restrict__ out)
{
  __shared__ __align__(16) unsigned char sAllB[4*10496];
  const int wv   = threadIdx.x >> 6;
  const int lane = threadIdx.x & 63;
  unsigned char* sA = sAllB + wv*10496;      // 2048 B staging
  unsigned char* gC = sA + 2048;             // 8448 B C tile

  const int i = blockIdx.x*4 + wv;
  const int n0 = offsets[i], n1 = offsets[i+1];
  const int cnt = n1 - n0;
  const int c    = lane & 31;
  const int l15  = lane & 15;
  const int quad = lane >> 4;
  const bool low = (lane < 32);

  // preload Wxm^T B-fragments (8 n-frags, K=32) into registers
  short8 b4[8];
  #pragma unroll
  for (int nf=0; nf<8; nf++)
    b4[nf] = ld_frag((const unsigned char*)wb4 + (16*nf + l15)*64 + quad*16);
  const float wvm_c = Wvm[c];

  // pass A: softmax denominators per head (contiguous float4 stream)
  float d0=0.f,d1=0.f,d2=0.f,d3=0.f;
  for (int s = n0 + lane; s < n1; s += 64){
    const float4 ev = *(const float4*)(e4 + (size_t)s*4);
    d0+=ev.x; d1+=ev.y; d2+=ev.z; d3+=ev.w;
  }
  #pragma unroll
  for (int off=32; off>=1; off>>=1){
    d0 += __shfl_xor(d0,off); d1 += __shfl_xor(d1,off);
    d2 += __shfl_xor(d2,off); d3 += __shfl_xor(d3,off);
  }
  const float i0 = (cnt>0)?1.f/d0:0.f, i1 = (cnt>0)?1.f/d1:0.f;
  const float i2 = (cnt>0)?1.f/d2:0.f, i3 = (cnt>0)?1.f/d3:0.f;

  float sem4[4] = {0.f,0.f,0.f,0.f};
  float cx=0.f,cy=0.f,cz=0.f, gx=0.f,gy=0.f,gz=0.f;

  // chunked main loop: 32 pairs per MFMA tile
  for (int base = n0; base < n1; base += 32){
    const int nc = min(32, n1 - base);
    // stage A: contiguous block copy (nc rows x 64 B)
    if (lane*32 < nc*64){
      const uint4* src = (const uint4*)(edgeb + (size_t)base*16 + lane*8);
      *(uint4*)(sA + lane*32)      = src[0];
      *(uint4*)(sA + lane*32 + 16) = src[1];
    }
    // GEMM: g[32 pairs][128 n] = A[32][32] @ Wxm^T[32][128]
    short8 a0 = ld_frag(sA + l15*64 + quad*16);
    short8 a1 = ld_frag(sA + (16+l15)*64 + quad*16);
    f32x4 accg[2][8];
    #pragma unroll
    for (int nf=0; nf<8; nf++){
      f32x4 z = (f32x4){0.f,0.f,0.f,0.f};
      accg[0][nf] = mfma16(a0, b4[nf], z);
      accg[1][nf] = mfma16(a1, b4[nf], z);
    }
    // C -> LDS bf16 [row][132 ushort] (264 B rows)
    #pragma unroll
    for (int mf=0; mf<2; mf++)
      #pragma unroll
      for (int nf=0; nf<8; nf++){
        int n = 16*nf + l15;
        #pragma unroll
        for (int reg=0; reg<4; reg++){
          int row = 16*mf + quad*4 + reg;
          ((unsigned short*)gC)[row*132 + n] = (unsigned short)f2b16(accg[mf][nf][reg]);
        }
      }
    // inner: 2 pairs per iteration (one per half-wave); all loads contiguous/LDS
    for (int t0 = 0; t0 < nc; t0 += 2){
      const int rloc = t0 + (lane >> 5);
      const bool act = rloc < nc;
      const int s = base + (act ? rloc : 0);
      const float4 ev = *(const float4*)(e4 + (size_t)s*4);
      const float4 dv = *(const float4*)(dir4 + (size_t)s*4);
      const float aw0 = ev.x*i0, aw1 = ev.y*i1, aw2 = ev.z*i2, aw3 = ev.w*i3;
      uint2 gv = *(const uint2*)(gC + rloc*264 + c*8);
      float g0=u2f(gv.x<<16), g1=u2f(gv.x&0xffff0000u);
      float g2=u2f(gv.y<<16), g3=u2f(gv.y&0xffff0000u);
      float tp = aw0*g0 + aw1*g1 + aw2*g2 + aw3*g3;
      float tt = fminf(fmaxf(tp, -15.f), 15.f);
      float ex = __expf(2.f*tt);
      float th = (ex-1.f)/(ex+1.f);
      unsigned int ew = *(const unsigned int*)(sA + rloc*64 + (c>>1)*4);
      float ec = (c & 1) ? u2f(ew & 0xffff0000u) : u2f(ew << 16);
      if (act){
        sem4[0] += ec*aw0; sem4[1] += ec*aw1;
        sem4[2] += ec*aw2; sem4[3] += ec*aw3;
        cx += th*dv.x; cy += th*dv.y; cz += th*dv.z;
        float tw = th*wvm_c;
        gx += tw*dv.x; gy += tw*dv.y; gz += tw*dv.z;
      }
    }
  }

  // cross-half combine (each half handled disjoint pairs)
  #pragma unroll
  for (int j=0;j<4;j++) sem4[j] += __shfl_xor(sem4[j], 32);
  cx += __shfl_xor(cx,32); cy += __shfl_xor(cy,32); cz += __shfl_xor(cz,32);
  #pragma unroll
  for (int off=32; off>=1; off>>=1){
    gx += __shfl_xor(gx,off); gy += __shfl_xor(gy,off); gz += __shfl_xor(gz,off);
  }
  const float invc = 1.f/(float)(cnt > 1 ? cnt : 1);
  const float dvx = gx*invc, dvy = gy*invc, dvz = gz*invc;

  // MLP scratch overlays sA (dead after chunk loop); wave-local, no barriers
  float* sIn = (float*)sA;              // 256 f32
  float* sN2 = (float*)(sA + 1024);     // 32
  float* sT  = (float*)(sA + 1152);     // 64
  float* sT2 = (float*)(sA + 1408);     // 64  (total 1664 <= 2048)

  if (low){
    float mx = cx*invc, my = cy*invc, mz = cz*invc;
    sN2[c] = mx*mx + my*my + mz*mz;
    *(float4*)(sIn + 64 + 4*c) = make_float4(sem4[0], sem4[1], sem4[2], sem4[3]);
  }
  sIn[lane] = h[(size_t)i*64 + lane];

  // spatial MLP: 32 -> 64 -> 64
  float s1 = bpn1[lane];
  #pragma unroll
  for (int cc=0;cc<32;cc++) s1 += sN2[cc]*Wpn1[cc*64+lane];
  s1 = silu_f(s1);
  sT[lane] = s1;
  float s2 = bpn2[lane];
  for (int o=0;o<64;o+=4){
    const float4 t4 = *(const float4*)(&sT[o]);
    s2 += t4.x*Wpn2[o*64+lane] + t4.y*Wpn2[(o+1)*64+lane]
        + t4.z*Wpn2[(o+2)*64+lane] + t4.w*Wpn2[(o+3)*64+lane];
  }
  sIn[192+lane] = silu_f(s2);

  // node MLP: 256 -> 64 -> 64, residual
  float b1 = bn1[lane];
  for (int m=0;m<256;m+=4){
    const float4 t4 = *(const float4*)(&sIn[m]);
    b1 += t4.x*Wn1[m*64+lane] + t4.y*Wn1[(m+1)*64+lane]
        + t4.z*Wn1[(m+2)*64+lane] + t4.w*Wn1[(m+3)*64+lane];
  }
  b1 = silu_f(b1);
  sT[lane] = b1;
  float b2 = bn2[lane];
  for (int m=0;m<64;m+=4){
    const float4 t4 = *(const float4*)(&sT[m]);
    b2 += t4.x*Wn2[m*64+lane] + t4.y*Wn2[(m+1)*64+lane]
        + t4.z*Wn2[(m+2)*64+lane] + t4.w*Wn2[(m+3)*64+lane];
  }
  const float hnew = sIn[lane] + silu_f(b2);
  out[(size_t)i*64 + lane] = hnew;
  sT2[lane] = hnew;

  // velocity gate: 64 -> 64 -> 1
  float c1 = bv1[lane];
  for (int m=0;m<64;m+=4){
    const float4 t4 = *(const float4*)(&sT2[m]);
    c1 += t4.x*Wv1[m*64+lane] + t4.y*Wv1[(m+1)*64+lane]
        + t4.z*Wv1[(m+2)*64+lane] + t4.w*Wv1[(m+3)*64+lane];
  }
  c1 = silu_f(c1);
  float gp = c1 * Wv2[lane];
  #pragma unroll
  for (int off=32; off>=1; off>>=1) gp += __shfl_xor(gp, off);
  const float gate = 2.f/(1.f + __expf(-gp));

  if (lane < 3){
    float vv = v[(size_t)i*3 + lane];
    float xx = x[(size_t)i*3 + lane];
    float ds = (lane==0) ? dvx : ((lane==1) ? dvy : dvz);
    float vn = gate*vv + ds;
    out[(size_t)N_*64 + (size_t)i*3 + lane]                 = xx + vn;
    out[(size_t)N_*64 + (size_t)N_*3 + (size_t)i*3 + lane]  = vn;
  }
}

// ---------------- launch ----------------
extern "C" void kernel_launch(void* const* d_in, const int* in_sizes, int n_in,
                              void* d_out, int out_size, void* d_ws, size_t ws_size,
                              hipStream_t stream)
{
  const float* h = (const float*)d_in[0];
  const float* x = (const float*)d_in[1];
  const float* v = (const float*)d_in[2];
  const int* idx_i = (const int*)d_in[3];
  const int* idx_j = (const int*)d_in[4];
  const float* Wein = (const float*)d_in[5];  const float* bein = (const float*)d_in[6];
  const float* Weo1 = (const float*)d_in[7];  const float* beo1 = (const float*)d_in[8];
  const float* Weo2 = (const float*)d_in[9];  const float* beo2 = (const float*)d_in[10];
  const float* Watt = (const float*)d_in[11]; const float* batt = (const float*)d_in[12];
  const float* Wxm  = (const float*)d_in[13]; const float* Wvm  = (const float*)d_in[14];
  const float* Wpn1 = (const float*)d_in[15]; const float* bpn1 = (const float*)d_in[16];
  const float* Wpn2 = (const float*)d_in[17]; const float* bpn2 = (const float*)d_in[18];
  const float* Wn1  = (const float*)d_in[19]; const float* bn1  = (const float*)d_in[20];
  const float* Wn2  = (const float*)d_in[21]; const float* bn2  = (const float*)d_in[22];
  const float* Wv1  = (const float*)d_in[23]; const float* bv1  = (const float*)d_in[24];
  const float* Wv2  = (const float*)d_in[25];

  float* wsf        = (float*)d_ws;
  int*   cnt        = (int*)(wsf + OFF_CNT);
  int*   offsets    = (int*)(wsf + OFF_OFFSETS);
  int*   cursor     = (int*)(wsf + OFF_CURSOR);
  int*   sorted     = (int*)(wsf + OFF_SORTED);
  unsigned int* edgeb = (unsigned int*)(wsf + OFF_EDGE);
  float* e4o        = wsf + OFF_E4;
  float* diro       = wsf + OFF_DIR;
  unsigned short* wb1 = (unsigned short*)(wsf + OFF_WB1);
  unsigned short* wb2 = (unsigned short*)(wsf + OFF_WB2);
  unsigned short* wb3 = (unsigned short*)(wsf + OFF_WB3);
  unsigned short* wb4 = (unsigned short*)(wsf + OFF_WB4);

  hipMemsetAsync(cnt, 0, N_*sizeof(int), stream);
  k_hist<<<(P_+255)/256, 256, 0, stream>>>(idx_i, cnt);
  k_scan<<<1, 1024, 0, stream>>>(cnt, offsets, cursor);
  // cnt dead after scan -> overlay transposed weights there
  k_prepw<<<32, 256, 0, stream>>>(Wein, Weo1, Weo2, Wxm, wb1, wb2, wb3, wb4);
  k_scatter<<<(P_+255)/256, 256, 0, stream>>>(idx_i, cursor, sorted);
  k_edge2<<<P_/128, 256, 0, stream>>>(h, x, idx_i, idx_j, sorted, wb1, wb2, wb3,
                                      bein, beo1, beo2, Watt, batt,
                                      edgeb, e4o, diro);
  k_node4<<<N_/4, 256, 0, stream>>>(h, x, v, offsets, edgeb, e4o, diro,
                                    wb4, Wvm, Wpn1, bpn1, Wpn2, bpn2,
                                    Wn1, bn1, Wn2, bn2, Wv1, bv1, Wv2,
                                    (float*)d_out);
}

// Round 6
// 398.401 us; speedup vs baseline: 2.7229x; 1.1339x over previous
//
#include <hip/hip_runtime.h>
#include <hip/hip_bf16.h>

#define DEV __device__ __forceinline__

constexpr int N_ = 25000;
constexpr int P_ = 400000;

// ---------------- ws layout (units of 4 bytes) ----------------
constexpr int align4(int xx){ return (xx+3)&~3; }
constexpr int OFF_CNT     = 0;                          // N ints (dead after k_scan)
constexpr int OFF_OFFSETS = align4(OFF_CNT + N_);       // N+1 ints
constexpr int OFF_CURSOR  = align4(OFF_OFFSETS + N_ + 1);
constexpr int OFF_SORTED  = align4(OFF_CURSOR + N_);    // P ints
constexpr int OFF_EDGE    = align4(OFF_SORTED + P_);    // P*16 dwords (32 bf16 edge feats, sorted order)
constexpr int OFF_E4      = OFF_EDGE + P_*16;           // P*4  f32
constexpr int OFF_DIR     = OFF_E4 + P_*4;              // P*4  f32
constexpr int OFF_SEM     = align4(OFF_DIR + P_*4);     // N*128 f32
constexpr int OFF_N2      = OFF_SEM + N_*128;           // N*32 f32
constexpr int OFF_DV      = OFF_N2 + N_*32;             // N*4 f32
constexpr int OFF_WB5     = OFF_DV + N_*4;              // wpn1T [64][32]  = 1024 dw
constexpr int OFF_WB6     = OFF_WB5 + 1024;             // wpn2T [64][64]  = 2048 dw
constexpr int OFF_WB7     = OFF_WB6 + 2048;             // wn1T  [64][256] = 8192 dw
constexpr int OFF_WB8     = OFF_WB7 + 8192;             // wn2T  [64][64]  = 2048 dw
constexpr int OFF_WB9     = OFF_WB8 + 2048;             // wv1T  [64][64]  = 2048 dw
constexpr int WS_UNITS    = OFF_WB9 + 2048;             // ~14.2M dw = 57 MB (ws >= 66 MB per r1)

// transposed bf16 edge weights overlaid on the dead cnt region (13312 dw <= 25000 dw)
constexpr int OFF_WB1 = OFF_CNT;          // [128 n][128 k] bf16 = 8192 dw
constexpr int OFF_WB2 = OFF_WB1 + 8192;   // [64 n][64 k]  bf16 = 2048 dw
constexpr int OFF_WB3 = OFF_WB2 + 2048;   // [32 n][64 k]  bf16 = 1024 dw
constexpr int OFF_WB4 = OFF_WB3 + 1024;   // [128 n][32 k] bf16 = 2048 dw (Wxm^T, n=4c+h)

// PhysNet RBF constants (K=50, r_max=0.5)
constexpr float MU0F  = 0.60653065971263342f;               // exp(-0.5)
constexpr float DMUF  = (1.0f - 0.60653065971263342f) / 49.0f;
constexpr float BETAF = 1.0f / ((0.04f * (1.0f - 0.60653065971263342f)) *
                                (0.04f * (1.0f - 0.60653065971263342f)));
constexpr float EPSF  = 1e-8f;

DEV float u2f(unsigned int u){ union{unsigned int i; float f;} c; c.i=u; return c.f; }
DEV unsigned int f2b16(float f){
  __hip_bfloat16 b = __float2bfloat16(f);
  unsigned short s; __builtin_memcpy(&s, &b, 2);
  return (unsigned int)s;
}
DEV unsigned int pack2(float a, float b){ return f2b16(a) | (f2b16(b) << 16); }
DEV float silu_f(float v){ return v / (1.0f + __expf(-v)); }

using short8 = __attribute__((ext_vector_type(8))) short;   // 8 bf16 (4 VGPRs)
using f32x4  = __attribute__((ext_vector_type(4))) float;
union U4S8 { uint4 u; short8 s; };
DEV short8 ld_frag(const void* p){ U4S8 c; c.u = *(const uint4*)p; return c.s; }
DEV f32x4 mfma16(short8 a, short8 b, f32x4 c){
  return __builtin_amdgcn_mfma_f32_16x16x32_bf16(a, b, c, 0, 0, 0);
}

// ---------------- counting sort by idx_i ----------------
__global__ void k_hist(const int* __restrict__ idx_i, int* __restrict__ cnt){
  int t = blockIdx.x*256 + threadIdx.x;
  if (t < P_) atomicAdd(&cnt[idx_i[t]], 1);
}

__global__ __launch_bounds__(1024) void k_scan(const int* __restrict__ cnt,
                                               int* __restrict__ offsets,
                                               int* __restrict__ cursor){
  __shared__ int swv[16];
  const int t = threadIdx.x;
  const int wv = t >> 6, ln = t & 63;
  constexpr int CH = (N_ + 1023)/1024;   // 25
  int b = t*CH, e = b+CH;
  if (b > N_) b = N_;
  if (e > N_) e = N_;
  int s = 0;
  for (int q=b; q<e; q++) s += cnt[q];
  int incl = s;
  #pragma unroll
  for (int off=1; off<64; off<<=1){
    int vv = __shfl_up(incl, off);
    if (ln >= off) incl += vv;
  }
  if (ln == 63) swv[wv] = incl;
  __syncthreads();
  if (wv == 0 && ln < 16){
    int w = swv[ln];
    #pragma unroll
    for (int off=1; off<16; off<<=1){
      int vv = __shfl_up(w, off);
      if (ln >= off) w += vv;
    }
    swv[ln] = w;
  }
  __syncthreads();
  const int wpre = (wv > 0) ? swv[wv-1] : 0;
  int run = wpre + incl - s;
  for (int q=b; q<e; q++){ offsets[q] = run; cursor[q] = run; run += cnt[q]; }
  if (t == 1023) offsets[N_] = run;
}

__global__ void k_scatter(const int* __restrict__ idx_i, int* __restrict__ cursor,
                          int* __restrict__ sorted){
  int t = blockIdx.x*256 + threadIdx.x;
  if (t < P_){ int pos = atomicAdd(&cursor[idx_i[t]], 1); sorted[pos] = t; }
}

// ---------------- weight transpose/convert to bf16 [N][K] ----------------
__global__ void k_prepw(const float* __restrict__ Wein, const float* __restrict__ Weo1,
                        const float* __restrict__ Weo2, const float* __restrict__ Wxm,
                        const float* __restrict__ Wpn1, const float* __restrict__ Wpn2,
                        const float* __restrict__ Wn1,  const float* __restrict__ Wn2,
                        const float* __restrict__ Wv1,
                        unsigned short* __restrict__ wb1, unsigned short* __restrict__ wb2,
                        unsigned short* __restrict__ wb3, unsigned short* __restrict__ wb4,
                        unsigned short* __restrict__ wb5, unsigned short* __restrict__ wb6,
                        unsigned short* __restrict__ wb7, unsigned short* __restrict__ wb8,
                        unsigned short* __restrict__ wb9){
  int t = blockIdx.x*256 + threadIdx.x, st = gridDim.x*256;
  for (int q=t; q<128*128; q+=st){
    int n=q>>7, k=q&127;
    float v = (n<50) ? Wein[k*50+n] : ((n<64) ? 0.f : Weo1[k*64+(n-64)]);
    wb1[q] = (unsigned short)f2b16(v);
  }
  for (int q=t; q<64*64; q+=st){
    int n=q>>6, k=q&63;
    float v = (k<50) ? Weo1[(128+k)*64+n] : ((k==50) ? Weo1[178*64+n] : 0.f);
    wb2[q] = (unsigned short)f2b16(v);
  }
  for (int q=t; q<32*64; q+=st){
    int n=q>>6, k=q&63;
    wb3[q] = (unsigned short)f2b16(Weo2[k*32+n]);
  }
  for (int q=t; q<128*32; q+=st){
    int n=q>>5, k=q&31;
    int cc = n>>2, hh = n&3;
    wb4[q] = (unsigned short)f2b16(Wxm[(k*4+hh)*32 + cc]);
  }
  for (int q=t; q<64*32; q+=st){ int n=q>>5, k=q&31;  wb5[q] = (unsigned short)f2b16(Wpn1[k*64+n]); }
  for (int q=t; q<64*64; q+=st){ int n=q>>6, k=q&63;  wb6[q] = (unsigned short)f2b16(Wpn2[k*64+n]); }
  for (int q=t; q<64*256;q+=st){ int n=q>>8, k=q&255; wb7[q] = (unsigned short)f2b16(Wn1[k*64+n]); }
  for (int q=t; q<64*64; q+=st){ int n=q>>6, k=q&63;  wb8[q] = (unsigned short)f2b16(Wn2[k*64+n]); }
  for (int q=t; q<64*64; q+=st){ int n=q>>6, k=q&63;  wb9[q] = (unsigned short)f2b16(Wv1[k*64+n]); }
}

// ---------------- MFMA edge kernel (unchanged, sorted order) ----------------
__global__ __launch_bounds__(256, 3) void k_edge2(
    const float* __restrict__ h, const float* __restrict__ x,
    const int* __restrict__ idx_i, const int* __restrict__ idx_j,
    const int* __restrict__ sorted,
    const unsigned short* __restrict__ wb1, const unsigned short* __restrict__ wb2,
    const unsigned short* __restrict__ wb3,
    const float* __restrict__ bein, const float* __restrict__ beo1,
    const float* __restrict__ beo2, const float* __restrict__ Watt,
    const float* __restrict__ batt,
    unsigned int* __restrict__ edge_out, float* __restrict__ e4_out,
    float* __restrict__ dir_out)
{
  __shared__ __align__(16) unsigned char sR1[128*264];
  __shared__ __align__(16) unsigned char sR2[128*144];
  __shared__ float sdv[128];
  __shared__ float semd[128];

  const int tid  = threadIdx.x;
  const int wv   = tid >> 6;
  const int lane = tid & 63;
  const int l15  = lane & 15;
  const int quad = lane >> 4;
  const int pbase = blockIdx.x * 128;

  if (lane < 32){
    int row = 32*wv + lane;
    int p2 = pbase + row;
    int pp = sorted[p2];
    int ii = idx_i[pp], jj = idx_j[pp];
    float xi0=x[ii*3], xi1=x[ii*3+1], xi2=x[ii*3+2];
    float xj0=x[jj*3], xj1=x[jj*3+1], xj2=x[jj*3+2];
    float rx=xj0-xi0, ry=xj1-xi1, rz=xj2-xi2;
    float d = sqrtf(rx*rx+ry*ry+rz*rz+EPSF);
    float iv = 1.0f/(d+EPSF);
    sdv[row] = d;
    semd[row] = __expf(-d);
    *(float4*)(dir_out + (size_t)p2*4) = make_float4(rx*iv, ry*iv, rz*iv, d);
  }

  {
    int rr = lane >> 1;
    int row = 32*wv + rr;
    int pp1 = sorted[pbase + row];
    int hidx = (lane & 1) ? idx_j[pp1] : idx_i[pp1];
    const float4* hp = (const float4*)(h + (size_t)hidx*64);
    unsigned char* dst = sR1 + row*264 + (lane&1)*128;
    #pragma unroll
    for (int q=0;q<8;q++){
      float4 a = hp[2*q], b = hp[2*q+1];
      uint4 o = make_uint4(pack2(a.x,a.y), pack2(a.z,a.w), pack2(b.x,b.y), pack2(b.z,b.w));
      *(uint4*)(dst + q*16) = o;
    }
  }

  f32x4 acc[2][8];
  #pragma unroll
  for (int mf=0; mf<2; mf++)
    #pragma unroll
    for (int nf=0; nf<8; nf++){
      float bias;
      if (nf < 4){ int nn = 16*nf + l15; bias = (nn < 50) ? bein[nn] : 0.f; }
      else       { bias = beo1[16*(nf-4) + l15]; }
      acc[mf][nf] = (f32x4){bias, bias, bias, bias};
    }
  #pragma unroll
  for (int s=0; s<4; s++){
    int koff = s*32 + quad*8;
    short8 a0 = ld_frag(sR1 + (32*wv + l15)*264      + koff*2);
    short8 a1 = ld_frag(sR1 + (32*wv + 16 + l15)*264 + koff*2);
    #pragma unroll
    for (int nf=0; nf<8; nf++){
      short8 b = ld_frag((const unsigned char*)wb1 + (16*nf + l15)*256 + koff*2);
      acc[0][nf] = mfma16(a0, b, acc[0][nf]);
      acc[1][nf] = mfma16(a1, b, acc[1][nf]);
    }
  }

  #pragma unroll
  for (int mf=0; mf<2; mf++)
    #pragma unroll
    for (int nf=0; nf<4; nf++){
      int n = 16*nf + l15;
      float mu = MU0F + (float)n*DMUF;
      #pragma unroll
      for (int reg=0; reg<4; reg++){
        int row = 32*wv + 16*mf + quad*4 + reg;
        float t = semd[row] - mu;
        float fv = acc[mf][nf][reg] * __expf(-BETAF*t*t);
        unsigned short ob;
        if (n < 50)       ob = (unsigned short)f2b16(fv);
        else if (n == 50) ob = (unsigned short)f2b16(sdv[row]);
        else              ob = 0;
        ((unsigned short*)sR2)[row*72 + n] = ob;
      }
    }

  #pragma unroll
  for (int s=0; s<2; s++){
    int koff = s*32 + quad*8;
    short8 a0 = ld_frag(sR2 + (32*wv + l15)*144      + koff*2);
    short8 a1 = ld_frag(sR2 + (32*wv + 16 + l15)*144 + koff*2);
    #pragma unroll
    for (int nf=0; nf<4; nf++){
      short8 b = ld_frag((const unsigned char*)wb2 + (16*nf + l15)*128 + koff*2);
      acc[0][4+nf] = mfma16(a0, b, acc[0][4+nf]);
      acc[1][4+nf] = mfma16(a1, b, acc[1][4+nf]);
    }
  }

  unsigned char* A3 = sR1 + 8448*wv;
  #pragma unroll
  for (int mf=0; mf<2; mf++)
    #pragma unroll
    for (int nf=0; nf<4; nf++){
      int n = 16*nf + l15;
      #pragma unroll
      for (int reg=0; reg<4; reg++){
        int rr = 16*mf + quad*4 + reg;
        ((unsigned short*)A3)[rr*72 + n] = (unsigned short)f2b16(silu_f(acc[mf][4+nf][reg]));
      }
    }

  f32x4 acc3[2][2];
  #pragma unroll
  for (int mf=0; mf<2; mf++)
    #pragma unroll
    for (int nf=0; nf<2; nf++){
      float bias = beo2[16*nf + l15];
      acc3[mf][nf] = (f32x4){bias, bias, bias, bias};
    }
  #pragma unroll
  for (int s=0; s<2; s++){
    int koff = s*32 + quad*8;
    short8 a0 = ld_frag(A3 + (l15)*144      + koff*2);
    short8 a1 = ld_frag(A3 + (16 + l15)*144 + koff*2);
    #pragma unroll
    for (int nf=0; nf<2; nf++){
      short8 b = ld_frag((const unsigned char*)wb3 + (16*nf + l15)*128 + koff*2);
      acc3[0][nf] = mfma16(a0, b, acc3[0][nf]);
      acc3[1][nf] = mfma16(a1, b, acc3[1][nf]);
    }
  }

  #pragma unroll
  for (int mf=0; mf<2; mf++)
    #pragma unroll
    for (int nf=0; nf<2; nf++){
      int n = 16*nf + l15;
      #pragma unroll
      for (int reg=0; reg<4; reg++){
        int row = 32*wv + 16*mf + quad*4 + reg;
        ((float*)sR2)[row*36 + n] = acc3[mf][nf][reg];
      }
    }

  {
    int rr = lane >> 1;
    int row = 32*wv + rr;
    int p = pbase + row;
    int cb = (lane & 1) * 16;
    const float* er = (const float*)sR2 + row*36;
    float l0, l1, l2, l3;
    if ((lane & 1) == 0){ l0 = batt[0]; l1 = batt[1]; l2 = batt[2]; l3 = batt[3]; }
    else                { l0 = l1 = l2 = l3 = 0.f; }
    float ecache[16];
    #pragma unroll
    for (int c=0;c<16;c++){
      float ev = er[cb + c];
      ecache[c] = ev;
      const float4 wr = *(const float4*)(Watt + (cb + c)*4);
      l0 += ev*wr.x; l1 += ev*wr.y; l2 += ev*wr.z; l3 += ev*wr.w;
    }
    l0 += __shfl_xor(l0,1); l1 += __shfl_xor(l1,1);
    l2 += __shfl_xor(l2,1); l3 += __shfl_xor(l3,1);
    if ((lane & 1) == 0){
      float e0 = __expf(l0 > 0.f ? l0 : 2.f*(__expf(l0*0.5f)-1.f));
      float e1 = __expf(l1 > 0.f ? l1 : 2.f*(__expf(l1*0.5f)-1.f));
      float e2 = __expf(l2 > 0.f ? l2 : 2.f*(__expf(l2*0.5f)-1.f));
      float e3 = __expf(l3 > 0.f ? l3 : 2.f*(__expf(l3*0.5f)-1.f));
      *(float4*)(e4_out + (size_t)p*4) = make_float4(e0, e1, e2, e3);
    }
    uint4 o1 = make_uint4(pack2(ecache[0],ecache[1]),  pack2(ecache[2],ecache[3]),
                          pack2(ecache[4],ecache[5]),  pack2(ecache[6],ecache[7]));
    uint4 o2 = make_uint4(pack2(ecache[8],ecache[9]),  pack2(ecache[10],ecache[11]),
                          pack2(ecache[12],ecache[13]),pack2(ecache[14],ecache[15]));
    unsigned int* ep = edge_out + (size_t)p*16 + (lane&1)*8;
    *(uint4*)(ep)     = o1;
    *(uint4*)(ep + 4) = o2;
  }
}

// ---------------- aggregation kernel: 4 waves/block, 4 nodes/wave ----------------
// Per-wave LDS 10240 B: sA [32][64 B] staging | gC [32][256 B]. 4 blocks/CU.
__global__ __launch_bounds__(256, 4) void k_agg(
    const int* __restrict__ offsets,
    const unsigned int* __restrict__ edgeb,
    const float* __restrict__ e4,
    const float* __restrict__ dir4,
    const unsigned short* __restrict__ wb4,
    const float* __restrict__ Wvm,
    float* __restrict__ wsSem, float* __restrict__ wsN2, float* __restrict__ wsDv)
{
  __shared__ __align__(16) unsigned char sAllB[4*10240];
  const int wv   = threadIdx.x >> 6;
  const int lane = threadIdx.x & 63;
  unsigned char* sA = sAllB + wv*10240;
  unsigned char* gC = sA + 2048;

  const int c    = lane & 31;
  const int l15  = lane & 15;
  const int quad = lane >> 4;
  const bool low = (lane < 32);

  short8 b4[8];
  #pragma unroll
  for (int nf=0; nf<8; nf++)
    b4[nf] = ld_frag((const unsigned char*)wb4 + (16*nf + l15)*64 + quad*16);
  const float wvm_c = Wvm[c];

  for (int q=0; q<4; q++){
    const int i = blockIdx.x*16 + wv*4 + q;
    if (i >= N_) break;
    const int n0 = offsets[i], n1 = offsets[i+1];
    const int cnt = n1 - n0;

    float d0=0.f,d1=0.f,d2=0.f,d3=0.f;
    for (int s = n0 + lane; s < n1; s += 64){
      const float4 ev = *(const float4*)(e4 + (size_t)s*4);
      d0+=ev.x; d1+=ev.y; d2+=ev.z; d3+=ev.w;
    }
    #pragma unroll
    for (int off=32; off>=1; off>>=1){
      d0 += __shfl_xor(d0,off); d1 += __shfl_xor(d1,off);
      d2 += __shfl_xor(d2,off); d3 += __shfl_xor(d3,off);
    }
    const float i0 = (cnt>0)?1.f/d0:0.f, i1 = (cnt>0)?1.f/d1:0.f;
    const float i2 = (cnt>0)?1.f/d2:0.f, i3 = (cnt>0)?1.f/d3:0.f;

    float sem4[4] = {0.f,0.f,0.f,0.f};
    float cx=0.f,cy=0.f,cz=0.f, gx=0.f,gy=0.f,gz=0.f;

    for (int base = n0; base < n1; base += 32){
      const int nc = min(32, n1 - base);
      if (lane*32 < nc*64){
        const uint4* src = (const uint4*)(edgeb + (size_t)base*16 + lane*8);
        *(uint4*)(sA + lane*32)      = src[0];
        *(uint4*)(sA + lane*32 + 16) = src[1];
      }
      short8 a0 = ld_frag(sA + l15*64 + quad*16);
      short8 a1 = ld_frag(sA + (16+l15)*64 + quad*16);
      f32x4 accg[2][8];
      #pragma unroll
      for (int nf=0; nf<8; nf++){
        f32x4 z = (f32x4){0.f,0.f,0.f,0.f};
        accg[0][nf] = mfma16(a0, b4[nf], z);
        accg[1][nf] = mfma16(a1, b4[nf], z);
      }
      #pragma unroll
      for (int mf=0; mf<2; mf++)
        #pragma unroll
        for (int nf=0; nf<8; nf++){
          int n = 16*nf + l15;
          #pragma unroll
          for (int reg=0; reg<4; reg++){
            int row = 16*mf + quad*4 + reg;
            ((unsigned short*)gC)[row*128 + n] = (unsigned short)f2b16(accg[mf][nf][reg]);
          }
        }
      for (int t0 = 0; t0 < nc; t0 += 2){
        const int rloc = t0 + (lane >> 5);
        const bool act = rloc < nc;
        const int s = base + (act ? rloc : 0);
        const float4 ev = *(const float4*)(e4 + (size_t)s*4);
        const float4 dv = *(const float4*)(dir4 + (size_t)s*4);
        const float aw0 = ev.x*i0, aw1 = ev.y*i1, aw2 = ev.z*i2, aw3 = ev.w*i3;
        uint2 gv = *(const uint2*)(gC + rloc*256 + c*8);
        float g0=u2f(gv.x<<16), g1=u2f(gv.x&0xffff0000u);
        float g2=u2f(gv.y<<16), g3=u2f(gv.y&0xffff0000u);
        float tp = aw0*g0 + aw1*g1 + aw2*g2 + aw3*g3;
        float tt = fminf(fmaxf(tp, -15.f), 15.f);
        float ex = __expf(2.f*tt);
        float th = (ex-1.f)/(ex+1.f);
        unsigned int ew = *(const unsigned int*)(sA + rloc*64 + (c>>1)*4);
        float ec = (c & 1) ? u2f(ew & 0xffff0000u) : u2f(ew << 16);
        if (act){
          sem4[0] += ec*aw0; sem4[1] += ec*aw1;
          sem4[2] += ec*aw2; sem4[3] += ec*aw3;
          cx += th*dv.x; cy += th*dv.y; cz += th*dv.z;
          float tw = th*wvm_c;
          gx += tw*dv.x; gy += tw*dv.y; gz += tw*dv.z;
        }
      }
    }

    #pragma unroll
    for (int j=0;j<4;j++) sem4[j] += __shfl_xor(sem4[j], 32);
    cx += __shfl_xor(cx,32); cy += __shfl_xor(cy,32); cz += __shfl_xor(cz,32);
    #pragma unroll
    for (int off=32; off>=1; off>>=1){
      gx += __shfl_xor(gx,off); gy += __shfl_xor(gy,off); gz += __shfl_xor(gz,off);
    }
    const float invc = 1.f/(float)(cnt > 1 ? cnt : 1);
    if (low){
      float mx = cx*invc, my = cy*invc, mz = cz*invc;
      wsN2[(size_t)i*32 + c] = mx*mx + my*my + mz*mz;
      *(float4*)(wsSem + (size_t)i*128 + 4*c) = make_float4(sem4[0], sem4[1], sem4[2], sem4[3]);
    }
    if (lane == 0)
      *(float4*)(wsDv + (size_t)i*4) = make_float4(gx*invc, gy*invc, gz*invc, 0.f);
  }
}

// ---------------- node MLP kernel: batched MFMA GEMM, 128 nodes/block ----------------
// LDS: sH[128][136] | sSem[128][264] | sSp[128][136] | sN2[128][72] | sTmp[128][136]
// One barrier after staging; thereafter each wave owns rows 32*wv..+31.
__global__ __launch_bounds__(256) void k_mlp(
    const float* __restrict__ h, const float* __restrict__ x, const float* __restrict__ v,
    const float* __restrict__ wsSem, const float* __restrict__ wsN2,
    const float* __restrict__ wsDv,
    const unsigned short* __restrict__ wb5, const unsigned short* __restrict__ wb6,
    const unsigned short* __restrict__ wb7, const unsigned short* __restrict__ wb8,
    const unsigned short* __restrict__ wb9,
    const float* __restrict__ bpn1, const float* __restrict__ bpn2,
    const float* __restrict__ bn1,  const float* __restrict__ bn2,
    const float* __restrict__ bv1,  const float* __restrict__ Wv2,
    float* __restrict__ out)
{
  __shared__ __align__(16) unsigned char sH[128*136];
  __shared__ __align__(16) unsigned char sSem[128*264];
  __shared__ __align__(16) unsigned char sSp[128*136];
  __shared__ __align__(16) unsigned char sN2[128*72];
  __shared__ __align__(16) unsigned char sTmp[128*136];

  const int tid  = threadIdx.x;
  const int wv   = tid >> 6;
  const int lane = tid & 63;
  const int l15  = lane & 15;
  const int quad = lane >> 4;
  const int i0   = blockIdx.x*128;
  const int r0   = 32*wv;

  // ---- stage h, sem, n2 (block-wide, coalesced) ----
  for (int idx = tid; idx < 128*16; idx += 256){
    int row = idx >> 4, c4 = idx & 15;
    int node = min(i0 + row, N_-1);
    float4 a = *(const float4*)(h + (size_t)node*64 + c4*4);
    *(uint2*)(sH + row*136 + c4*8) = make_uint2(pack2(a.x,a.y), pack2(a.z,a.w));
  }
  for (int idx = tid; idx < 128*32; idx += 256){
    int row = idx >> 5, c4 = idx & 31;
    int node = min(i0 + row, N_-1);
    float4 a = *(const float4*)(wsSem + (size_t)node*128 + c4*4);
    *(uint2*)(sSem + row*264 + c4*8) = make_uint2(pack2(a.x,a.y), pack2(a.z,a.w));
  }
  for (int idx = tid; idx < 128*8; idx += 256){
    int row = idx >> 3, c4 = idx & 7;
    int node = min(i0 + row, N_-1);
    float4 a = *(const float4*)(wsN2 + (size_t)node*32 + c4*4);
    *(uint2*)(sN2 + row*72 + c4*8) = make_uint2(pack2(a.x,a.y), pack2(a.z,a.w));
  }
  __syncthreads();

  // ---- S1: s1 = silu(n2 @ Wpn1 + b)  (K=32) ----
  {
    f32x4 acc[2][4];
    #pragma unroll
    for (int mf=0; mf<2; mf++)
      #pragma unroll
      for (int nf=0; nf<4; nf++){ float b = bpn1[16*nf+l15]; acc[mf][nf] = (f32x4){b,b,b,b}; }
    short8 a0 = ld_frag(sN2 + (r0+l15)*72 + quad*16);
    short8 a1 = ld_frag(sN2 + (r0+16+l15)*72 + quad*16);
    #pragma unroll
    for (int nf=0; nf<4; nf++){
      short8 b = ld_frag((const unsigned char*)wb5 + (16*nf+l15)*64 + quad*16);
      acc[0][nf] = mfma16(a0, b, acc[0][nf]);
      acc[1][nf] = mfma16(a1, b, acc[1][nf]);
    }
    #pragma unroll
    for (int mf=0; mf<2; mf++)
      #pragma unroll
      for (int nf=0; nf<4; nf++){
        int n = 16*nf + l15;
        #pragma unroll
        for (int reg=0; reg<4; reg++){
          int row = r0 + 16*mf + quad*4 + reg;
          ((unsigned short*)(sTmp + row*136))[n] = (unsigned short)f2b16(silu_f(acc[mf][nf][reg]));
        }
      }
  }
  // ---- S2: spatial = silu(s1 @ Wpn2 + b)  (K=64) ----
  {
    f32x4 acc[2][4];
    #pragma unroll
    for (int mf=0; mf<2; mf++)
      #pragma unroll
      for (int nf=0; nf<4; nf++){ float b = bpn2[16*nf+l15]; acc[mf][nf] = (f32x4){b,b,b,b}; }
    #pragma unroll
    for (int s=0; s<2; s++){
      int koff = s*32 + quad*8;
      short8 a0 = ld_frag(sTmp + (r0+l15)*136 + koff*2);
      short8 a1 = ld_frag(sTmp + (r0+16+l15)*136 + koff*2);
      #pragma unroll
      for (int nf=0; nf<4; nf++){
        short8 b = ld_frag((const unsigned char*)wb6 + (16*nf+l15)*128 + koff*2);
        acc[0][nf] = mfma16(a0, b, acc[0][nf]);
        acc[1][nf] = mfma16(a1, b, acc[1][nf]);
      }
    }
    #pragma unroll
    for (int mf=0; mf<2; mf++)
      #pragma unroll
      for (int nf=0; nf<4; nf++){
        int n = 16*nf + l15;
        #pragma unroll
        for (int reg=0; reg<4; reg++){
          int row = r0 + 16*mf + quad*4 + reg;
          ((unsigned short*)(sSp + row*136))[n] = (unsigned short)f2b16(silu_f(acc[mf][nf][reg]));
        }
      }
  }
  // ---- N1: b1 = silu([h|sem|sp] @ Wn1 + b)  (K=256) ----
  {
    f32x4 acc[2][4];
    #pragma unroll
    for (int mf=0; mf<2; mf++)
      #pragma unroll
      for (int nf=0; nf<4; nf++){ float b = bn1[16*nf+l15]; acc[mf][nf] = (f32x4){b,b,b,b}; }
    #pragma unroll
    for (int s=0; s<8; s++){
      int koff = s*32 + quad*8;
      const unsigned char *pa0, *pa1;
      if (koff < 64){ pa0 = sH + (r0+l15)*136 + koff*2;          pa1 = sH + (r0+16+l15)*136 + koff*2; }
      else if (koff < 192){ pa0 = sSem + (r0+l15)*264 + (koff-64)*2;  pa1 = sSem + (r0+16+l15)*264 + (koff-64)*2; }
      else { pa0 = sSp + (r0+l15)*136 + (koff-192)*2;            pa1 = sSp + (r0+16+l15)*136 + (koff-192)*2; }
      short8 a0 = ld_frag(pa0);
      short8 a1 = ld_frag(pa1);
      #pragma unroll
      for (int nf=0; nf<4; nf++){
        short8 b = ld_frag((const unsigned char*)wb7 + (16*nf+l15)*512 + koff*2);
        acc[0][nf] = mfma16(a0, b, acc[0][nf]);
        acc[1][nf] = mfma16(a1, b, acc[1][nf]);
      }
    }
    #pragma unroll
    for (int mf=0; mf<2; mf++)
      #pragma unroll
      for (int nf=0; nf<4; nf++){
        int n = 16*nf + l15;
        #pragma unroll
        for (int reg=0; reg<4; reg++){
          int row = r0 + 16*mf + quad*4 + reg;
          ((unsigned short*)(sTmp + row*136))[n] = (unsigned short)f2b16(silu_f(acc[mf][nf][reg]));
        }
      }
  }
  // ---- N2: hnew = h + silu(b1 @ Wn2 + b); write out + sH(bf16) ----
  {
    f32x4 acc[2][4];
    #pragma unroll
    for (int mf=0; mf<2; mf++)
      #pragma unroll
      for (int nf=0; nf<4; nf++){ float b = bn2[16*nf+l15]; acc[mf][nf] = (f32x4){b,b,b,b}; }
    #pragma unroll
    for (int s=0; s<2; s++){
      int koff = s*32 + quad*8;
      short8 a0 = ld_frag(sTmp + (r0+l15)*136 + koff*2);
      short8 a1 = ld_frag(sTmp + (r0+16+l15)*136 + koff*2);
      #pragma unroll
      for (int nf=0; nf<4; nf++){
        short8 b = ld_frag((const unsigned char*)wb8 + (16*nf+l15)*128 + koff*2);
        acc[0][nf] = mfma16(a0, b, acc[0][nf]);
        acc[1][nf] = mfma16(a1, b, acc[1][nf]);
      }
    }
    #pragma unroll
    for (int mf=0; mf<2; mf++)
      #pragma unroll
      for (int nf=0; nf<4; nf++){
        int n = 16*nf + l15;
        #pragma unroll
        for (int reg=0; reg<4; reg++){
          int row = r0 + 16*mf + quad*4 + reg;
          int node = i0 + row;
          float hv = (node < N_) ? h[(size_t)node*64 + n] : 0.f;
          float hnew = hv + silu_f(acc[mf][nf][reg]);
          if (node < N_) out[(size_t)node*64 + n] = hnew;
          ((unsigned short*)(sH + row*136))[n] = (unsigned short)f2b16(hnew);
        }
      }
  }
  // ---- V1 + gate + v/x update ----
  {
    f32x4 acc[2][4];
    #pragma unroll
    for (int mf=0; mf<2; mf++)
      #pragma unroll
      for (int nf=0; nf<4; nf++){ float b = bv1[16*nf+l15]; acc[mf][nf] = (f32x4){b,b,b,b}; }
    #pragma unroll
    for (int s=0; s<2; s++){
      int koff = s*32 + quad*8;
      short8 a0 = ld_frag(sH + (r0+l15)*136 + koff*2);
      short8 a1 = ld_frag(sH + (r0+16+l15)*136 + koff*2);
      #pragma unroll
      for (int nf=0; nf<4; nf++){
        short8 b = ld_frag((const unsigned char*)wb9 + (16*nf+l15)*128 + koff*2);
        acc[0][nf] = mfma16(a0, b, acc[0][nf]);
        acc[1][nf] = mfma16(a1, b, acc[1][nf]);
      }
    }
    float part[2][4] = {{0.f,0.f,0.f,0.f},{0.f,0.f,0.f,0.f}};
    #pragma unroll
    for (int mf=0; mf<2; mf++)
      #pragma unroll
      for (int nf=0; nf<4; nf++){
        float w2 = Wv2[16*nf + l15];
        #pragma unroll
        for (int reg=0; reg<4; reg++)
          part[mf][reg] += silu_f(acc[mf][nf][reg]) * w2;
      }
    #pragma unroll
    for (int mf=0; mf<2; mf++)
      #pragma unroll
      for (int reg=0; reg<4; reg++){
        #pragma unroll
        for (int off=1; off<16; off<<=1)
          part[mf][reg] += __shfl_xor(part[mf][reg], off);
      }
    if (l15 == 0){
      #pragma unroll
      for (int mf=0; mf<2; mf++)
        #pragma unroll
        for (int reg=0; reg<4; reg++){
          int row = r0 + 16*mf + quad*4 + reg;
          int node = i0 + row;
          if (node < N_){
            float gate = 2.f/(1.f + __expf(-part[mf][reg]));
            float4 dvv = *(const float4*)(wsDv + (size_t)node*4);
            float dvs[3] = {dvv.x, dvv.y, dvv.z};
            #pragma unroll
            for (int ax=0; ax<3; ax++){
              float vn = gate * v[(size_t)node*3 + ax] + dvs[ax];
              out[(size_t)N_*64 + (size_t)node*3 + ax]                 = x[(size_t)node*3 + ax] + vn;
              out[(size_t)N_*64 + (size_t)N_*3 + (size_t)node*3 + ax]  = vn;
            }
          }
        }
    }
  }
}

// ---------------- launch ----------------
extern "C" void kernel_launch(void* const* d_in, const int* in_sizes, int n_in,
                              void* d_out, int out_size, void* d_ws, size_t ws_size,
                              hipStream_t stream)
{
  const float* h = (const float*)d_in[0];
  const float* x = (const float*)d_in[1];
  const float* v = (const float*)d_in[2];
  const int* idx_i = (const int*)d_in[3];
  const int* idx_j = (const int*)d_in[4];
  const float* Wein = (const float*)d_in[5];  const float* bein = (const float*)d_in[6];
  const float* Weo1 = (const float*)d_in[7];  const float* beo1 = (const float*)d_in[8];
  const float* Weo2 = (const float*)d_in[9];  const float* beo2 = (const float*)d_in[10];
  const float* Watt = (const float*)d_in[11]; const float* batt = (const float*)d_in[12];
  const float* Wxm  = (const float*)d_in[13]; const float* Wvm  = (const float*)d_in[14];
  const float* Wpn1 = (const float*)d_in[15]; const float* bpn1 = (const float*)d_in[16];
  const float* Wpn2 = (const float*)d_in[17]; const float* bpn2 = (const float*)d_in[18];
  const float* Wn1  = (const float*)d_in[19]; const float* bn1  = (const float*)d_in[20];
  const float* Wn2  = (const float*)d_in[21]; const float* bn2  = (const float*)d_in[22];
  const float* Wv1  = (const float*)d_in[23]; const float* bv1  = (const float*)d_in[24];
  const float* Wv2  = (const float*)d_in[25];

  float* wsf        = (float*)d_ws;
  int*   cnt        = (int*)(wsf + OFF_CNT);
  int*   offsets    = (int*)(wsf + OFF_OFFSETS);
  int*   cursor     = (int*)(wsf + OFF_CURSOR);
  int*   sorted     = (int*)(wsf + OFF_SORTED);
  unsigned int* edgeb = (unsigned int*)(wsf + OFF_EDGE);
  float* e4o        = wsf + OFF_E4;
  float* diro       = wsf + OFF_DIR;
  float* wsSem      = wsf + OFF_SEM;
  float* wsN2       = wsf + OFF_N2;
  float* wsDv       = wsf + OFF_DV;
  unsigned short* wb1 = (unsigned short*)(wsf + OFF_WB1);
  unsigned short* wb2 = (unsigned short*)(wsf + OFF_WB2);
  unsigned short* wb3 = (unsigned short*)(wsf + OFF_WB3);
  unsigned short* wb4 = (unsigned short*)(wsf + OFF_WB4);
  unsigned short* wb5 = (unsigned short*)(wsf + OFF_WB5);
  unsigned short* wb6 = (unsigned short*)(wsf + OFF_WB6);
  unsigned short* wb7 = (unsigned short*)(wsf + OFF_WB7);
  unsigned short* wb8 = (unsigned short*)(wsf + OFF_WB8);
  unsigned short* wb9 = (unsigned short*)(wsf + OFF_WB9);

  hipMemsetAsync(cnt, 0, N_*sizeof(int), stream);
  k_hist<<<(P_+255)/256, 256, 0, stream>>>(idx_i, cnt);
  k_scan<<<1, 1024, 0, stream>>>(cnt, offsets, cursor);
  k_prepw<<<32, 256, 0, stream>>>(Wein, Weo1, Weo2, Wxm, Wpn1, Wpn2, Wn1, Wn2, Wv1,
                                  wb1, wb2, wb3, wb4, wb5, wb6, wb7, wb8, wb9);
  k_scatter<<<(P_+255)/256, 256, 0, stream>>>(idx_i, cursor, sorted);
  k_edge2<<<P_/128, 256, 0, stream>>>(h, x, idx_i, idx_j, sorted, wb1, wb2, wb3,
                                      bein, beo1, beo2, Watt, batt,
                                      edgeb, e4o, diro);
  k_agg<<<(N_+15)/16, 256, 0, stream>>>(offsets, edgeb, e4o, diro, wb4, Wvm,
                                        wsSem, wsN2, wsDv);
  k_mlp<<<(N_+127)/128, 256, 0, stream>>>(h, x, v, wsSem, wsN2, wsDv,
                                          wb5, wb6, wb7, wb8, wb9,
                                          bpn1, bpn2, bn1, bn2, bv1, Wv2,
                                          (float*)d_out);
}